// Round 1
// baseline (340.627 us; speedup 1.0000x reference)
//
#include <hip/hip_runtime.h>
#include <hip/hip_bf16.h>

typedef unsigned int u32;
typedef unsigned short u16;
typedef float f32x4 __attribute__((ext_vector_type(4)));
typedef short bh8 __attribute__((ext_vector_type(8)));   // 8 bf16 operand frag

#define NB 16
#define NN 128
#define DD 128

__device__ __forceinline__ u16 f2bf(float f) {
  union { float f; u32 u; } x; x.f = f;
  u32 r = (x.u + 0x7fffu + ((x.u >> 16) & 1u)) >> 16;
  return (u16)r;
}
__device__ __forceinline__ float bf2f(u16 h) {
  union { u32 u; float f; } x; x.u = ((u32)h) << 16;
  return x.f;
}
__device__ __forceinline__ float lrelu(float x) { return x >= 0.f ? x : 0.01f * x; }

// ---------------- weight conversion ----------------
__global__ void k_cvt(const float* __restrict__ src, u16* __restrict__ dst, int n) {
  int i = blockIdx.x * 256 + threadIdx.x;
  if (i < n) dst[i] = f2bf(src[i]);
}
// src [G][R][C] -> dst [G][C][R]
__global__ void k_cvt_t(const float* __restrict__ src, u16* __restrict__ dst, int R, int C) {
  int g = blockIdx.y;
  int i = blockIdx.x * 256 + threadIdx.x;
  if (i < R * C) {
    int r = i / C, c = i % C;
    dst[(size_t)g * R * C + (size_t)c * R + r] = f2bf(src[(size_t)g * R * C + i]);
  }
}

// ---------------- point-sim fused MLP (the big one) ----------------
// block = (b,i); computes s[b,i,j] and sims for j-tiles >= i-tile, mirrors writes.
__global__ __launch_bounds__(256, 2)
void k_point_sim(const float* __restrict__ vp,
                 const u16* __restrict__ w1,     // bf16 [256][128]
                 const float* __restrict__ g1v, const float* __restrict__ b1v,
                 const u16* __restrict__ w2,     // bf16 [128][256]
                 const float* __restrict__ g2v, const float* __restrict__ b2v,
                 const float* __restrict__ w3v, const float* __restrict__ b3v,
                 float* __restrict__ s_out, float* __restrict__ sims_out)
{
  const int b = blockIdx.x >> 7;
  const int i = blockIdx.x & 127;
  const int t = threadIdx.x;
  const int lane = t & 63;
  const int w = t >> 6;
  const int jt0 = i >> 4;
  const int j0 = jt0 << 4;
  const int NJ = NN - j0;
  const float rsbn = rsqrtf(1.0f + 1e-5f);

  __shared__ u16 Adiff[NN * DD];   // 32KB, swizzled bf16 diff [j][d]
  __shared__ u16 HL[NN * 128];     // 32KB, swizzled bf16 h1-half [j][cl]
  __shared__ float vis[DD];
  __shared__ float sred[4][NN];

  if (t < 32) ((float4*)vis)[t] = ((const float4*)(vp + (size_t)(b * NN + i) * DD))[t];
  __syncthreads();

  // phase 0: diff rows j >= j0, bf16 into Adiff (swizzled), fp32 rowsum -> sims
  {
    int jj = t >> 1;
    if (jj < NJ) {
      int j = j0 + jj;
      int dbase = (t & 1) * 64;
      const float* vr = vp + (size_t)(b * NN + j) * DD + dbase;
      const float* vi = vis + dbase;
      float rs = 0.f;
      #pragma unroll
      for (int c = 0; c < 8; ++c) {
        float4 a0 = ((const float4*)vr)[2 * c];
        float4 a1 = ((const float4*)vr)[2 * c + 1];
        float4 i0 = ((const float4*)vi)[2 * c];
        float4 i1 = ((const float4*)vi)[2 * c + 1];
        float d0 = i0.x - a0.x; d0 *= d0;
        float d1 = i0.y - a0.y; d1 *= d1;
        float d2 = i0.z - a0.z; d2 *= d2;
        float d3 = i0.w - a0.w; d3 *= d3;
        float d4 = i1.x - a1.x; d4 *= d4;
        float d5 = i1.y - a1.y; d5 *= d5;
        float d6 = i1.z - a1.z; d6 *= d6;
        float d7 = i1.w - a1.w; d7 *= d7;
        rs += d0 + d1 + d2 + d3 + d4 + d5 + d6 + d7;
        uint4 pk;
        pk.x = (u32)f2bf(d0) | ((u32)f2bf(d1) << 16);
        pk.y = (u32)f2bf(d2) | ((u32)f2bf(d3) << 16);
        pk.z = (u32)f2bf(d4) | ((u32)f2bf(d5) << 16);
        pk.w = (u32)f2bf(d6) | ((u32)f2bf(d7) << 16);
        int dstart = dbase + c * 8;
        int byte = j * 256 + ((dstart * 2) ^ ((j & 7) << 4));
        *(uint4*)((char*)Adiff + byte) = pk;
      }
      rs += __shfl_xor(rs, 1);
      if ((t & 1) == 0) {
        sims_out[(size_t)(b * NN + i) * NN + j] = -rs;
        if (j != i) sims_out[(size_t)(b * NN + j) * NN + i] = -rs;
      }
    }
  }
  __syncthreads();

  f32x4 acc2[2][8];
  #pragma unroll
  for (int a = 0; a < 2; ++a)
    #pragma unroll
    for (int m = 0; m < 8; ++m) acc2[a][m] = f32x4{0.f, 0.f, 0.f, 0.f};

  #pragma unroll
  for (int hf = 0; hf < 2; ++hf) {
    // ---- layer 1 (half): h1^T[c, j] = sum_d W1[c,d] * diff[j,d] ----
    f32x4 acc1[2][8];
    #pragma unroll
    for (int a = 0; a < 2; ++a)
      #pragma unroll
      for (int m = 0; m < 8; ++m) acc1[a][m] = f32x4{0.f, 0.f, 0.f, 0.f};

    const int ctb = hf * 8 + w * 2;
    #pragma unroll
    for (int ks = 0; ks < 4; ++ks) {
      int d = ks * 32 + (lane >> 4) * 8;
      int c0 = ctb * 16 + (lane & 15);
      bh8 a0 = *(const bh8*)(w1 + c0 * DD + d);
      bh8 a1 = *(const bh8*)(w1 + (c0 + 16) * DD + d);
      #pragma unroll
      for (int jt = 0; jt < 8; ++jt) {
        if (jt >= jt0) {
          int j = jt * 16 + (lane & 15);
          int byte = j * 256 + ((d * 2) ^ ((j & 7) << 4));
          bh8 bfr = *(const bh8*)((const char*)Adiff + byte);
          acc1[0][jt] = __builtin_amdgcn_mfma_f32_16x16x32_bf16(a0, bfr, acc1[0][jt], 0, 0, 0);
          acc1[1][jt] = __builtin_amdgcn_mfma_f32_16x16x32_bf16(a1, bfr, acc1[1][jt], 0, 0, 0);
        }
      }
    }
    // epilogue: BN + lrelu + bf16 -> HL[j][cl]  (cl = local c in [0,128))
    #pragma unroll
    for (int ctl = 0; ctl < 2; ++ctl) {
      int clb = (w * 2 + ctl) * 16 + (lane >> 4) * 4;
      int cg = hf * 128 + clb;
      float4 gg = *(const float4*)(g1v + cg);
      float4 bb = *(const float4*)(b1v + cg);
      float sc0 = gg.x * rsbn, sc1 = gg.y * rsbn, sc2 = gg.z * rsbn, sc3 = gg.w * rsbn;
      #pragma unroll
      for (int jt = 0; jt < 8; ++jt) {
        if (jt >= jt0) {
          int j = jt * 16 + (lane & 15);
          f32x4 v = acc1[ctl][jt];
          u16 u0 = f2bf(lrelu(v[0] * sc0 + bb.x));
          u16 u1 = f2bf(lrelu(v[1] * sc1 + bb.y));
          u16 u2 = f2bf(lrelu(v[2] * sc2 + bb.z));
          u16 u3 = f2bf(lrelu(v[3] * sc3 + bb.w));
          uint2 pk;
          pk.x = (u32)u0 | ((u32)u1 << 16);
          pk.y = (u32)u2 | ((u32)u3 << 16);
          int byte = j * 256 + ((clb * 2) ^ ((j & 7) << 4));
          *(uint2*)((char*)HL + byte) = pk;
        }
      }
    }
    __syncthreads();
    // ---- layer 2 partial: h2[j,e] += sum_{c in half} h1[j,c] * W2[e,c] ----
    #pragma unroll
    for (int ks = 0; ks < 4; ++ks) {
      int cg = hf * 128 + ks * 32 + (lane >> 4) * 8;
      int cl2 = ks * 32 + (lane >> 4) * 8;
      int e0 = (w * 2) * 16 + (lane & 15);
      bh8 b0 = *(const bh8*)(w2 + e0 * 256 + cg);
      bh8 b1 = *(const bh8*)(w2 + (e0 + 16) * 256 + cg);
      #pragma unroll
      for (int mt = 0; mt < 8; ++mt) {
        if (mt >= jt0) {
          int j = mt * 16 + (lane & 15);
          int byte = j * 256 + ((cl2 * 2) ^ ((j & 7) << 4));
          bh8 af = *(const bh8*)((const char*)HL + byte);
          acc2[0][mt] = __builtin_amdgcn_mfma_f32_16x16x32_bf16(af, b0, acc2[0][mt], 0, 0, 0);
          acc2[1][mt] = __builtin_amdgcn_mfma_f32_16x16x32_bf16(af, b1, acc2[1][mt], 0, 0, 0);
        }
      }
    }
    __syncthreads();
  }

  // ---- layer-2 BN + lrelu, dot w3, reduce, sigmoid ----
  {
    float p[8][4];
    #pragma unroll
    for (int m = 0; m < 8; ++m)
      #pragma unroll
      for (int r = 0; r < 4; ++r) p[m][r] = 0.f;

    #pragma unroll
    for (int ntl = 0; ntl < 2; ++ntl) {
      int e = (w * 2 + ntl) * 16 + (lane & 15);
      float sc = g2v[e] * rsbn;
      float bc = b2v[e];
      float wv = w3v[e];
      #pragma unroll
      for (int mt = 0; mt < 8; ++mt) {
        if (mt >= jt0) {
          f32x4 v = acc2[ntl][mt];
          #pragma unroll
          for (int r = 0; r < 4; ++r) p[mt][r] += lrelu(v[r] * sc + bc) * wv;
        }
      }
    }
    #pragma unroll
    for (int mt = 0; mt < 8; ++mt) {
      if (mt >= jt0) {
        #pragma unroll
        for (int r = 0; r < 4; ++r) {
          float v = p[mt][r];
          v += __shfl_xor(v, 1);
          v += __shfl_xor(v, 2);
          v += __shfl_xor(v, 4);
          v += __shfl_xor(v, 8);
          if ((lane & 15) == 0) sred[w][mt * 16 + (lane >> 4) * 4 + r] = v;
        }
      }
    }
  }
  __syncthreads();
  if (t < NJ) {
    int j = j0 + t;
    float z = sred[0][j] + sred[1][j] + sred[2][j] + sred[3][j] + b3v[0];
    float sv = 1.f / (1.f + __expf(-z));
    s_out[(size_t)(b * NN + i) * NN + j] = sv;
    if (j != i) s_out[(size_t)(b * NN + j) * NN + i] = sv;
  }
}

// ---------------- top-k rank scatter (gen 1): mask[b, i, rank_n(i)] = 1 ----------------
__global__ void k_rank(const float* __restrict__ s_buf, const float* __restrict__ ep_prev,
                       float* __restrict__ mask)
{
  const int b = blockIdx.x >> 7, n = blockIdx.x & 127, t = threadIdx.x; // 128 threads
  __shared__ float ev[NN];
  size_t row = (size_t)(b * NN + n) * NN;
  float v = s_buf[row + t] * ((t == n) ? 0.f : ep_prev[row + t]);
  ev[t] = v;
  __syncthreads();
  int r = 0;
  for (int j = 0; j < NN; ++j) {
    float vj = ev[j];
    r += (vj > v) || (vj == v && j < t);
  }
  if (r < 115) mask[(size_t)(b * NN + t) * NN + r] = 1.0f;
}

// ---------------- edge normalization: e -> eps_out[g] ----------------
__global__ void k_edge(const float* __restrict__ s_buf, const float* __restrict__ ep_prev,
                       const float* __restrict__ mask, int use_mask,
                       float* __restrict__ eps_out)
{
  const int b = blockIdx.x >> 7, i = blockIdx.x & 127, t = threadIdx.x; // 128
  const int w = t >> 6, lane = t & 63;
  __shared__ float red[2][2];
  __shared__ float red2[2];
  size_t row = (size_t)(b * NN + i) * NN;
  float ep0 = (t == i) ? 0.f : ep_prev[row + t];
  float e = s_buf[row + t] * ep0;
  if (use_mask) e *= mask[row + t];
  float a = ep0, c = fabsf(e);
  #pragma unroll
  for (int o = 32; o; o >>= 1) { a += __shfl_xor(a, o); c += __shfl_xor(c, o); }
  if (lane == 0) { red[w][0] = a; red[w][1] = c; }
  __syncthreads();
  float epsum = red[0][0] + red[1][0];
  float l1 = red[0][1] + red[1][1];
  e = e / fmaxf(l1, 1e-12f) * epsum;
  e += ((t == i) ? 1.f : 0.f) + 1e-6f;
  float d = e;
  #pragma unroll
  for (int o = 32; o; o >>= 1) d += __shfl_xor(d, o);
  if (lane == 0) red2[w] = d;
  __syncthreads();
  eps_out[row + t] = e / (red2[0] + red2[1]);
}

// ---------------- q/k projections ----------------
__global__ __launch_bounds__(256) void k_qk(const float* __restrict__ vp,
    const u16* __restrict__ wqt, const u16* __restrict__ wkt,
    float* __restrict__ qo, float* __restrict__ ko)
{
  const int b = blockIdx.x >> 7, n = blockIdx.x & 127, t = threadIdx.x; // 256
  __shared__ float vr[DD];
  if (t < 128) vr[t] = vp[(size_t)(b * NN + n) * DD + t];
  __syncthreads();
  int o = t & 127;
  const u16* W = (t >> 7) ? wkt : wqt;   // [d][o] transposed
  float acc = 0.f;
  for (int d = 0; d < 128; ++d) acc += vr[d] * bf2f(W[d * 128 + o]);
  float* dst = (t >> 7) ? ko : qo;
  dst[(size_t)(b * NN + n) * 128 + o] = acc;
}

// ---------------- attention + fuse + l1norm -> efn ----------------
__global__ __launch_bounds__(256) void k_attn_fuse(
    const float* __restrict__ q, const float* __restrict__ k,
    const float* __restrict__ eps_g, float* __restrict__ efn)
{
  const int b = blockIdx.x >> 3, chunk = blockIdx.x & 7; // 16*8 blocks
  const int t = threadIdx.x, w = t >> 6, lane = t & 63;
  __shared__ float kk[NN * 130];
  __shared__ float qs[16 * DD];
  for (int idx = t; idx < NN * DD / 4; idx += 256) {
    int j = idx >> 5, c4 = idx & 31;
    float4 v = ((const float4*)(k + (size_t)b * NN * DD))[idx];
    kk[j * 130 + c4 * 4 + 0] = v.x;
    kk[j * 130 + c4 * 4 + 1] = v.y;
    kk[j * 130 + c4 * 4 + 2] = v.z;
    kk[j * 130 + c4 * 4 + 3] = v.w;
  }
  for (int idx = t; idx < 16 * DD; idx += 256)
    qs[idx] = q[(size_t)(b * NN + chunk * 16) * DD + idx];
  __syncthreads();
  #pragma unroll
  for (int rr = 0; rr < 4; ++rr) {
    int il = w * 4 + rr;
    int i = chunk * 16 + il;
    float a0 = 0.f, a1 = 0.f;
    #pragma unroll
    for (int h = 0; h < 8; ++h) {
      float l0 = 0.f, l1 = 0.f;
      #pragma unroll
      for (int d = 0; d < 16; ++d) {
        float qv = qs[il * DD + h * 16 + d];
        l0 += qv * kk[lane * 130 + h * 16 + d];
        l1 += qv * kk[(lane + 64) * 130 + h * 16 + d];
      }
      l0 *= 0.25f; l1 *= 0.25f;
      float m = fmaxf(l0, l1);
      #pragma unroll
      for (int o = 32; o; o >>= 1) m = fmaxf(m, __shfl_xor(m, o));
      float p0 = __expf(l0 - m), p1 = __expf(l1 - m);
      float sm = p0 + p1;
      #pragma unroll
      for (int o = 32; o; o >>= 1) sm += __shfl_xor(sm, o);
      float inv = 1.f / sm;
      a0 += p0 * inv; a1 += p1 * inv;
    }
    a0 *= 0.125f; a1 *= 0.125f;
    size_t row = (size_t)(b * NN + i) * NN;
    float e0 = eps_g[row + lane], e1 = eps_g[row + lane + 64];
    float f0 = 0.5f * (e0 + a0), f1 = 0.5f * (e1 + a1);
    if (lane == i) f0 = 0.f;
    if (lane + 64 == i) f1 = 0.f;
    float sabs = fabsf(f0) + fabsf(f1);
    #pragma unroll
    for (int o = 32; o; o >>= 1) sabs += __shfl_xor(sabs, o);
    float inv = 1.f / fmaxf(sabs, 1e-12f);
    efn[row + lane] = f0 * inv;
    efn[row + lane + 64] = f1 * inv;
  }
}

// ---------------- d2p: aggr + 2-layer MLP -> new vp ----------------
__global__ __launch_bounds__(256) void k_d2p(
    const float* __restrict__ efn, const float* __restrict__ vp,
    const u16* __restrict__ w1t, const float* __restrict__ g1v, const float* __restrict__ b1v,
    const u16* __restrict__ w2t, const float* __restrict__ g2v, const float* __restrict__ b2v,
    float* __restrict__ vpo)
{
  const int b = blockIdx.x >> 7, i = blockIdx.x & 127, t = threadIdx.x;
  const float rsbn = rsqrtf(1.0f + 1e-5f);
  __shared__ float er[NN];
  __shared__ float feat[256];
  __shared__ float h1s[256];
  __shared__ float pt[2][128];
  size_t row = (size_t)(b * NN + i);
  if (t < 128) { er[t] = efn[row * NN + t]; feat[t] = vp[row * DD + t]; }
  __syncthreads();
  {
    int d = t & 127, hh = t >> 7;
    float acc = 0.f;
    for (int j = hh * 64; j < hh * 64 + 64; ++j)
      acc += er[j] * vp[(size_t)(b * NN + j) * DD + d];
    pt[hh][d] = acc;
  }
  __syncthreads();
  if (t < 128) feat[128 + t] = pt[0][t] + pt[1][t];
  __syncthreads();
  {
    float acc = 0.f;
    for (int qq = 0; qq < 256; ++qq) acc += feat[qq] * bf2f(w1t[qq * 256 + t]);
    h1s[t] = lrelu(acc * (g1v[t] * rsbn) + b1v[t]);
  }
  __syncthreads();
  if (t < 128) {
    float acc = 0.f;
    for (int qq = 0; qq < 256; ++qq) acc += h1s[qq] * bf2f(w2t[qq * 128 + t]);
    vpo[row * DD + t] = lrelu(acc * (g2v[t] * rsbn) + b2v[t]);
  }
}

extern "C" void kernel_launch(void* const* d_in, const int* in_sizes, int n_in,
                              void* d_out, int out_size, void* d_ws, size_t ws_size,
                              hipStream_t stream)
{
  (void)in_sizes; (void)n_in; (void)out_size; (void)ws_size;
  const float* vp_in  = (const float*)d_in[0];
  const float* ep_in  = (const float*)d_in[1];
  const float* ps_w1  = (const float*)d_in[2];
  const float* ps_g1  = (const float*)d_in[3];
  const float* ps_b1  = (const float*)d_in[4];
  const float* ps_w2  = (const float*)d_in[5];
  const float* ps_g2  = (const float*)d_in[6];
  const float* ps_b2  = (const float*)d_in[7];
  const float* ps_w3  = (const float*)d_in[8];
  const float* ps_b3  = (const float*)d_in[9];
  const float* d2p_w1 = (const float*)d_in[10];
  const float* d2p_g1 = (const float*)d_in[11];
  const float* d2p_b1 = (const float*)d_in[12];
  const float* d2p_w2 = (const float*)d_in[13];
  const float* d2p_g2 = (const float*)d_in[14];
  const float* d2p_b2 = (const float*)d_in[15];
  const float* wq     = (const float*)d_in[16];
  const float* wk     = (const float*)d_in[17];

  float* out = (float*)d_out;
  float* eps_base  = out;                 // [2][16][128][128]
  float* sims_base = out + 524288;        // [2][16][128][128]
  float* vp_out    = out + 1048576;       // [16][128][128]

  char* ws = (char*)d_ws;
  float* s_buf = (float*)(ws + ((size_t)0 << 20));
  float* maskb = (float*)(ws + ((size_t)1 << 20));
  float* qb    = (float*)(ws + ((size_t)2 << 20));
  float* kb    = (float*)(ws + ((size_t)3 << 20));
  float* efnb  = (float*)(ws + ((size_t)4 << 20));
  float* vp1   = (float*)(ws + ((size_t)5 << 20));
  u16* w1bf  = (u16*)(ws + ((size_t)6 << 20));   // [2][256][128]
  u16* w2bf  = w1bf + 65536;                     // [2][128][256]
  u16* d2w1t = w2bf + 65536;                     // [2][256][256] (transposed [q][o])
  u16* d2w2t = d2w1t + 131072;                   // [2][256][128] (transposed)
  u16* wqt   = d2w2t + 65536;                    // [2][128][128] (transposed)
  u16* wkt   = wqt + 32768;

  k_cvt<<<dim3(256), 256, 0, stream>>>(ps_w1, w1bf, 65536);
  k_cvt<<<dim3(256), 256, 0, stream>>>(ps_w2, w2bf, 65536);
  k_cvt_t<<<dim3(256, 2), 256, 0, stream>>>(d2p_w1, d2w1t, 256, 256);
  k_cvt_t<<<dim3(128, 2), 256, 0, stream>>>(d2p_w2, d2w2t, 128, 256);
  k_cvt_t<<<dim3(64, 2), 256, 0, stream>>>(wq, wqt, 128, 128);
  k_cvt_t<<<dim3(64, 2), 256, 0, stream>>>(wk, wkt, 128, 128);

  for (int g = 0; g < 2; ++g) {
    const float* vpc = g ? (const float*)vp1 : vp_in;
    float* vpn = g ? vp_out : vp1;
    float* eps_g  = eps_base + (size_t)g * 262144;
    float* sims_g = sims_base + (size_t)g * 262144;
    const float* epprev = g ? eps_base : ep_in;

    k_point_sim<<<dim3(2048), 256, 0, stream>>>(vpc,
        w1bf + (size_t)g * 32768, ps_g1 + g * 256, ps_b1 + g * 256,
        w2bf + (size_t)g * 32768, ps_g2 + g * 128, ps_b2 + g * 128,
        ps_w3 + g * 128, ps_b3 + g, s_buf, sims_g);
    if (g) {
      hipMemsetAsync(maskb, 0, (size_t)262144 * 4, stream);
      k_rank<<<dim3(2048), 128, 0, stream>>>(s_buf, epprev, maskb);
    }
    k_edge<<<dim3(2048), 128, 0, stream>>>(s_buf, epprev, maskb, g, eps_g);
    k_qk<<<dim3(2048), 256, 0, stream>>>(vpc, wqt + (size_t)g * 16384, wkt + (size_t)g * 16384, qb, kb);
    k_attn_fuse<<<dim3(128), 256, 0, stream>>>(qb, kb, eps_g, efnb);
    k_d2p<<<dim3(2048), 256, 0, stream>>>(efnb, vpc,
        d2w1t + (size_t)g * 65536, d2p_g1 + g * 256, d2p_b1 + g * 256,
        d2w2t + (size_t)g * 32768, d2p_g2 + g * 128, d2p_b2 + g * 128, vpn);
  }
}

// Round 2
// 225.715 us; speedup vs baseline: 1.5091x; 1.5091x over previous
//
#include <hip/hip_runtime.h>
#include <hip/hip_bf16.h>

typedef unsigned int u32;
typedef unsigned short u16;
typedef float f32x4 __attribute__((ext_vector_type(4)));
typedef float f32x16 __attribute__((ext_vector_type(16)));
typedef short bh8 __attribute__((ext_vector_type(8)));   // 8 bf16 operand frag

#define NB 16
#define NN 128
#define DD 128

__device__ __forceinline__ u16 f2bf(float f) {
  union { float f; u32 u; } x; x.f = f;
  u32 r = (x.u + 0x7fffu + ((x.u >> 16) & 1u)) >> 16;
  return (u16)r;
}
__device__ __forceinline__ float bf2f(u16 h) {
  union { u32 u; float f; } x; x.u = ((u32)h) << 16;
  return x.f;
}
__device__ __forceinline__ float lrelu(float x) { return x >= 0.f ? x : 0.01f * x; }
__device__ __forceinline__ f32x16 zero16() {
  f32x16 v;
  #pragma unroll
  for (int r = 0; r < 16; ++r) v[r] = 0.f;
  return v;
}

// ---------------- unified weight pack/convert ----------------
// segA w1p:  frag-packed W1 for 32x32x16 A-operand: [(ct*8+ks)*64+lane]*8+r
//            = W1[g][ct*32+(lane&31)][ks*16+(lane>>5)*8+r]
// segB w2p:  frag-packed W2: [(et*16+ks2)*64+lane]*8+r
//            = W2[g][et*32+(lane&31)][ks2*16+(lane>>5)*8+r]
// segC d2w1t [g][q][o]=d2p_w1[g][o][q]; segD d2w2t; segE wqt; segF wkt
__global__ void k_pack(const float* __restrict__ ps_w1, const float* __restrict__ ps_w2,
                       const float* __restrict__ d2p_w1, const float* __restrict__ d2p_w2,
                       const float* __restrict__ wq, const float* __restrict__ wk,
                       u16* __restrict__ w1p, u16* __restrict__ w2p,
                       u16* __restrict__ d2w1t, u16* __restrict__ d2w2t,
                       u16* __restrict__ wqt, u16* __restrict__ wkt)
{
  int idx = blockIdx.x * 256 + threadIdx.x;
  if (idx < 65536) {
    int r = idx & 7, lane = (idx >> 3) & 63, f = (idx >> 9) & 63, g = idx >> 15;
    int ct = f >> 3, ks = f & 7;
    int c = ct * 32 + (lane & 31), d = ks * 16 + (lane >> 5) * 8 + r;
    w1p[idx] = f2bf(ps_w1[(size_t)g * 32768 + c * 128 + d]);
    return;
  }
  idx -= 65536;
  if (idx < 65536) {
    int r = idx & 7, lane = (idx >> 3) & 63, f = (idx >> 9) & 63, g = idx >> 15;
    int et = f >> 4, ks2 = f & 15;
    int e = et * 32 + (lane & 31), c = ks2 * 16 + (lane >> 5) * 8 + r;
    w2p[idx] = f2bf(ps_w2[(size_t)g * 32768 + e * 256 + c]);
    return;
  }
  idx -= 65536;
  if (idx < 131072) {
    int o = idx & 255, q = (idx >> 8) & 255, g = idx >> 16;
    d2w1t[idx] = f2bf(d2p_w1[(size_t)g * 65536 + o * 256 + q]);
    return;
  }
  idx -= 131072;
  if (idx < 65536) {
    int o = idx & 127, q = (idx >> 7) & 255, g = idx >> 15;
    d2w2t[idx] = f2bf(d2p_w2[(size_t)g * 32768 + o * 256 + q]);
    return;
  }
  idx -= 65536;
  if (idx < 32768) {
    int o = idx & 127, d = (idx >> 7) & 127, g = idx >> 14;
    wqt[idx] = f2bf(wq[(size_t)g * 16384 + o * 128 + d]);
    return;
  }
  idx -= 32768;
  if (idx < 32768) {
    int o = idx & 127, d = (idx >> 7) & 127, g = idx >> 14;
    wkt[idx] = f2bf(wk[(size_t)g * 16384 + o * 128 + d]);
    return;
  }
}

// ---------------- point-sim fused MLP, tile-pair blocks, 32x32x16 MFMA ----------------
// grid = 16 b * 36 (ti<=tj) pairs * 2 halves; each half does 4 m-tiles of 32 pairs.
__global__ __launch_bounds__(256, 2)
void k_point_sim(const float* __restrict__ vp,
                 const u16* __restrict__ w1p, const u16* __restrict__ w2p,
                 const float* __restrict__ g1v, const float* __restrict__ b1v,
                 const float* __restrict__ g2v, const float* __restrict__ b2v,
                 const float* __restrict__ w3v, const float* __restrict__ b3v,
                 float* __restrict__ s_out, float* __restrict__ sims_out)
{
  const int bid = blockIdx.x;
  const int half = bid & 1;
  int rem = (bid >> 1) % 36;
  const int b = (bid >> 1) / 36;
  int ti = 0;
  while (rem >= 8 - ti) { rem -= 8 - ti; ++ti; }
  const int tj = ti + rem;

  const int t = threadIdx.x;
  const int lane = t & 63;
  const int w = t >> 6;
  const int p_l = lane & 31;
  const int hi = lane >> 5;
  const float rsbn = rsqrtf(1.0f + 1e-5f);

  __shared__ u16 Adiff[32 * 128];   // 8KB  swizzled diff [p][d]
  __shared__ u16 HL[32 * 256];      // 16KB swizzled h1   [p][c]
  __shared__ float sc1[256], bb1[256];
  __shared__ float sc2[128], bb2[128], w3s[128];
  __shared__ float sred[4][32];

  sc1[t] = g1v[t] * rsbn; bb1[t] = b1v[t];
  if (t < 128) { sc2[t] = g2v[t] * rsbn; bb2[t] = b2v[t]; w3s[t] = w3v[t]; }

  // weight fragments in registers
  bh8 a1[2][8];
  #pragma unroll
  for (int c2 = 0; c2 < 2; ++c2)
    #pragma unroll
    for (int ks = 0; ks < 8; ++ks)
      a1[c2][ks] = *(const bh8*)(w1p + (((w * 2 + c2) * 8 + ks) * 64 + lane) * 8);
  bh8 a2[16];
  #pragma unroll
  for (int ks = 0; ks < 16; ++ks)
    a2[ks] = *(const bh8*)(w2p + ((w * 16 + ks) * 64 + lane) * 8);

  const int mtA = half * 4;
  const float* vpb = vp + (size_t)b * NN * DD;

  auto diffgen = [&](int mt) {
    int p = t >> 3, dseg = t & 7;
    int il = mt * 2 + (p >> 4), jl = p & 15;
    int i = ti * 16 + il, j = tj * 16 + jl;
    const float4* vi = (const float4*)(vpb + i * DD + dseg * 16);
    const float4* vj = (const float4*)(vpb + j * DD + dseg * 16);
    float rs = 0.f;
    u32 pw[8];
    #pragma unroll
    for (int c = 0; c < 4; ++c) {
      float4 av = vi[c], bv = vj[c];
      float d0 = av.x - bv.x; d0 *= d0;
      float d1 = av.y - bv.y; d1 *= d1;
      float d2 = av.z - bv.z; d2 *= d2;
      float d3 = av.w - bv.w; d3 *= d3;
      rs += d0 + d1 + d2 + d3;
      pw[c * 2]     = (u32)f2bf(d0) | ((u32)f2bf(d1) << 16);
      pw[c * 2 + 1] = (u32)f2bf(d2) | ((u32)f2bf(d3) << 16);
    }
    int base = p * 256;
    int off0 = (dseg * 32) ^ ((p & 15) << 4);
    int off1 = (dseg * 32 + 16) ^ ((p & 15) << 4);
    uint4 q0; q0.x = pw[0]; q0.y = pw[1]; q0.z = pw[2]; q0.w = pw[3];
    uint4 q1; q1.x = pw[4]; q1.y = pw[5]; q1.z = pw[6]; q1.w = pw[7];
    *(uint4*)((char*)Adiff + base + off0) = q0;
    *(uint4*)((char*)Adiff + base + off1) = q1;
    rs += __shfl_xor(rs, 1);
    rs += __shfl_xor(rs, 2);
    rs += __shfl_xor(rs, 4);
    if ((t & 7) == 0) {
      sims_out[(size_t)(b * NN + i) * NN + j] = -rs;
      if (ti != tj) sims_out[(size_t)(b * NN + j) * NN + i] = -rs;
    }
  };

  auto s_final = [&](int mt) {
    if (t < 32) {
      float z = sred[0][t] + sred[1][t] + sred[2][t] + sred[3][t] + b3v[0];
      float sv = 1.f / (1.f + __expf(-z));
      int P = mt * 32 + t;
      int il = P >> 4, jl = P & 15;
      int i = ti * 16 + il, j = tj * 16 + jl;
      s_out[(size_t)(b * NN + i) * NN + j] = sv;
      if (ti != tj) s_out[(size_t)(b * NN + j) * NN + i] = sv;
    }
  };

  diffgen(mtA);
  __syncthreads();

  for (int m = 0; m < 4; ++m) {
    const int mt = mtA + m;
    if (m > 0) s_final(mt - 1);

    // ---- layer 1: D[c][p] = W1 * diff^T ; transpose-write -> HL[p][c] ----
    f32x16 acc1[2];
    acc1[0] = zero16(); acc1[1] = zero16();
    #pragma unroll
    for (int ks = 0; ks < 8; ++ks) {
      int byte = p_l * 256 + ((ks * 32 + hi * 16) ^ ((p_l & 15) << 4));
      bh8 bf = *(const bh8*)((const char*)Adiff + byte);
      acc1[0] = __builtin_amdgcn_mfma_f32_32x32x16_bf16(a1[0][ks], bf, acc1[0], 0, 0, 0);
      acc1[1] = __builtin_amdgcn_mfma_f32_32x32x16_bf16(a1[1][ks], bf, acc1[1], 0, 0, 0);
    }
    #pragma unroll
    for (int c2 = 0; c2 < 2; ++c2) {
      #pragma unroll
      for (int g4 = 0; g4 < 4; ++g4) {
        int c0 = (w * 2 + c2) * 32 + g4 * 8 + hi * 4;
        float v0 = lrelu(acc1[c2][g4 * 4 + 0] * sc1[c0 + 0] + bb1[c0 + 0]);
        float v1 = lrelu(acc1[c2][g4 * 4 + 1] * sc1[c0 + 1] + bb1[c0 + 1]);
        float v2 = lrelu(acc1[c2][g4 * 4 + 2] * sc1[c0 + 2] + bb1[c0 + 2]);
        float v3 = lrelu(acc1[c2][g4 * 4 + 3] * sc1[c0 + 3] + bb1[c0 + 3]);
        uint2 pk;
        pk.x = (u32)f2bf(v0) | ((u32)f2bf(v1) << 16);
        pk.y = (u32)f2bf(v2) | ((u32)f2bf(v3) << 16);
        int byte = p_l * 512 + ((c0 * 2) ^ (p_l << 4));
        *(uint2*)((char*)HL + byte) = pk;
      }
    }
    __syncthreads();

    if (m < 3) diffgen(mt + 1);

    // ---- layer 2: D[e][p] = W2 * h1^T ----
    f32x16 acc2 = zero16();
    #pragma unroll
    for (int ks2 = 0; ks2 < 16; ++ks2) {
      int byte = p_l * 512 + ((ks2 * 32 + hi * 16) ^ (p_l << 4));
      bh8 bf = *(const bh8*)((const char*)HL + byte);
      acc2 = __builtin_amdgcn_mfma_f32_32x32x16_bf16(a2[ks2], bf, acc2, 0, 0, 0);
    }
    // epilogue: BN + lrelu + dot w3 over this wave's 32 e-rows
    {
      float psum = 0.f;
      #pragma unroll
      for (int r = 0; r < 16; ++r) {
        int e = w * 32 + (r & 3) + 8 * (r >> 2) + 4 * hi;
        float v = lrelu(acc2[r] * sc2[e] + bb2[e]);
        psum += v * w3s[e];
      }
      psum += __shfl_xor(psum, 32);
      if (hi == 0) sred[w][p_l] = psum;
    }
    __syncthreads();
  }
  s_final(mtA + 3);
}

// ---------------- top-k rank scatter (gen 1): mask[b, i, rank_n(i)] = 1 ----------------
__global__ void k_rank(const float* __restrict__ s_buf, const float* __restrict__ ep_prev,
                       float* __restrict__ mask)
{
  const int b = blockIdx.x >> 7, n = blockIdx.x & 127, t = threadIdx.x; // 128 threads
  __shared__ float ev[NN];
  size_t row = (size_t)(b * NN + n) * NN;
  float v = s_buf[row + t] * ((t == n) ? 0.f : ep_prev[row + t]);
  ev[t] = v;
  __syncthreads();
  int r = 0;
  for (int j = 0; j < NN; ++j) {
    float vj = ev[j];
    r += (vj > v) || (vj == v && j < t);
  }
  if (r < 115) mask[(size_t)(b * NN + t) * NN + r] = 1.0f;
}

// ---------------- edge normalization: e -> eps_out[g]; gen0 also zeroes maskb ----------------
__global__ void k_edge(const float* __restrict__ s_buf, const float* __restrict__ ep_prev,
                       float* __restrict__ maskb, int use_mask,
                       float* __restrict__ eps_out)
{
  const int b = blockIdx.x >> 7, i = blockIdx.x & 127, t = threadIdx.x; // 128
  const int w = t >> 6, lane = t & 63;
  __shared__ float red[2][2];
  __shared__ float red2[2];
  size_t row = (size_t)(b * NN + i) * NN;
  float ep0 = (t == i) ? 0.f : ep_prev[row + t];
  float e = s_buf[row + t] * ep0;
  if (use_mask) e *= maskb[row + t];
  else maskb[(size_t)blockIdx.x * 128 + t] = 0.f;   // prep for gen1's k_rank
  float a = ep0, c = fabsf(e);
  #pragma unroll
  for (int o = 32; o; o >>= 1) { a += __shfl_xor(a, o); c += __shfl_xor(c, o); }
  if (lane == 0) { red[w][0] = a; red[w][1] = c; }
  __syncthreads();
  float epsum = red[0][0] + red[1][0];
  float l1 = red[0][1] + red[1][1];
  e = e / fmaxf(l1, 1e-12f) * epsum;
  e += ((t == i) ? 1.f : 0.f) + 1e-6f;
  float d = e;
  #pragma unroll
  for (int o = 32; o; o >>= 1) d += __shfl_xor(d, o);
  if (lane == 0) red2[w] = d;
  __syncthreads();
  eps_out[row + t] = e / (red2[0] + red2[1]);
}

// ---------------- q/k projections ----------------
__global__ __launch_bounds__(256) void k_qk(const float* __restrict__ vp,
    const u16* __restrict__ wqt, const u16* __restrict__ wkt,
    float* __restrict__ qo, float* __restrict__ ko)
{
  const int b = blockIdx.x >> 7, n = blockIdx.x & 127, t = threadIdx.x; // 256
  __shared__ float vr[DD];
  if (t < 128) vr[t] = vp[(size_t)(b * NN + n) * DD + t];
  __syncthreads();
  int o = t & 127;
  const u16* W = (t >> 7) ? wkt : wqt;   // [d][o] transposed
  float acc = 0.f;
  for (int d = 0; d < 128; ++d) acc += vr[d] * bf2f(W[d * 128 + o]);
  float* dst = (t >> 7) ? ko : qo;
  dst[(size_t)(b * NN + n) * 128 + o] = acc;
}

// ---------------- fused attention + fuse + l1norm + d2p ----------------
__global__ __launch_bounds__(256) void k_attn_d2p(
    const float* __restrict__ q, const float* __restrict__ k,
    const float* __restrict__ eps_g, const float* __restrict__ vp,
    const u16* __restrict__ w1t, const float* __restrict__ g1v, const float* __restrict__ b1v,
    const u16* __restrict__ w2t, const float* __restrict__ g2v, const float* __restrict__ b2v,
    float* __restrict__ vpo)
{
  const int b = blockIdx.x >> 7, i = blockIdx.x & 127, t = threadIdx.x;
  const int lane = t & 63, w = t >> 6;
  const float rsbn = rsqrtf(1.0f + 1e-5f);
  __shared__ float qs[128];
  __shared__ float att[8 * 130];
  __shared__ float ef[128];
  __shared__ float feat[256];
  __shared__ float hh[256];
  __shared__ float red[2];
  __shared__ float pt[2][128];
  size_t row = (size_t)(b * NN + i);
  if (t < 128) qs[t] = q[row * 128 + t];
  __syncthreads();
  {
    int h = t >> 5, s = t & 31;
    float qh[16];
    #pragma unroll
    for (int d = 0; d < 16; ++d) qh[d] = qs[h * 16 + d];
    const float* kb = k + (size_t)b * NN * DD + h * 16;
    float lg[4];
    #pragma unroll
    for (int r = 0; r < 4; ++r) {
      const float4* kr = (const float4*)(kb + (s + 32 * r) * 128);
      float acc = 0.f;
      #pragma unroll
      for (int c = 0; c < 4; ++c) {
        float4 kv = kr[c];
        acc += qh[c*4+0]*kv.x + qh[c*4+1]*kv.y + qh[c*4+2]*kv.z + qh[c*4+3]*kv.w;
      }
      lg[r] = acc * 0.25f;
    }
    float m = fmaxf(fmaxf(lg[0], lg[1]), fmaxf(lg[2], lg[3]));
    #pragma unroll
    for (int o = 16; o; o >>= 1) m = fmaxf(m, __shfl_xor(m, o));
    float e0 = __expf(lg[0] - m), e1 = __expf(lg[1] - m);
    float e2 = __expf(lg[2] - m), e3 = __expf(lg[3] - m);
    float sm = e0 + e1 + e2 + e3;
    #pragma unroll
    for (int o = 16; o; o >>= 1) sm += __shfl_xor(sm, o);
    float inv = 1.f / sm;
    att[h * 130 + s]      = e0 * inv;
    att[h * 130 + s + 32] = e1 * inv;
    att[h * 130 + s + 64] = e2 * inv;
    att[h * 130 + s + 96] = e3 * inv;
  }
  __syncthreads();
  if (t < 128) {
    float a = 0.f;
    #pragma unroll
    for (int h = 0; h < 8; ++h) a += att[h * 130 + t];
    a *= 0.125f;
    float f = 0.5f * (eps_g[row * 128 + t] + a);
    if (t == i) f = 0.f;
    float sab = fabsf(f);
    #pragma unroll
    for (int o = 32; o; o >>= 1) sab += __shfl_xor(sab, o);
    if (lane == 0) red[w] = sab;
    ef[t] = f;
  }
  __syncthreads();
  {
    float inv = 1.f / fmaxf(red[0] + red[1], 1e-12f);
    int d = t & 127, hf = t >> 7;
    const float* vpb = vp + (size_t)b * NN * DD;
    float acc = 0.f;
    for (int j = hf * 64; j < hf * 64 + 64; ++j)
      acc += ef[j] * vpb[j * 128 + d];
    pt[hf][d] = acc * inv;
  }
  __syncthreads();
  if (t < 128) { feat[t] = vp[row * 128 + t]; feat[128 + t] = pt[0][t] + pt[1][t]; }
  __syncthreads();
  {
    float acc = 0.f;
    for (int q2 = 0; q2 < 256; ++q2) acc += feat[q2] * bf2f(w1t[q2 * 256 + t]);
    hh[t] = lrelu(acc * (g1v[t] * rsbn) + b1v[t]);
  }
  __syncthreads();
  if (t < 128) {
    float acc = 0.f;
    for (int q2 = 0; q2 < 256; ++q2) acc += hh[q2] * bf2f(w2t[q2 * 128 + t]);
    vpo[row * 128 + t] = lrelu(acc * (g2v[t] * rsbn) + b2v[t]);
  }
}

extern "C" void kernel_launch(void* const* d_in, const int* in_sizes, int n_in,
                              void* d_out, int out_size, void* d_ws, size_t ws_size,
                              hipStream_t stream)
{
  (void)in_sizes; (void)n_in; (void)out_size; (void)ws_size;
  const float* vp_in  = (const float*)d_in[0];
  const float* ep_in  = (const float*)d_in[1];
  const float* ps_w1  = (const float*)d_in[2];
  const float* ps_g1  = (const float*)d_in[3];
  const float* ps_b1  = (const float*)d_in[4];
  const float* ps_w2  = (const float*)d_in[5];
  const float* ps_g2  = (const float*)d_in[6];
  const float* ps_b2  = (const float*)d_in[7];
  const float* ps_w3  = (const float*)d_in[8];
  const float* ps_b3  = (const float*)d_in[9];
  const float* d2p_w1 = (const float*)d_in[10];
  const float* d2p_g1 = (const float*)d_in[11];
  const float* d2p_b1 = (const float*)d_in[12];
  const float* d2p_w2 = (const float*)d_in[13];
  const float* d2p_g2 = (const float*)d_in[14];
  const float* d2p_b2 = (const float*)d_in[15];
  const float* wq     = (const float*)d_in[16];
  const float* wk     = (const float*)d_in[17];

  float* out = (float*)d_out;
  float* eps_base  = out;                 // [2][16][128][128]
  float* sims_base = out + 524288;        // [2][16][128][128]
  float* vp_out    = out + 1048576;       // [16][128][128]

  char* ws = (char*)d_ws;
  float* s_buf = (float*)(ws + ((size_t)0 << 20));
  float* maskb = (float*)(ws + ((size_t)1 << 20));
  float* qb    = (float*)(ws + ((size_t)2 << 20));
  float* kb    = (float*)(ws + ((size_t)3 << 20));
  float* vp1   = (float*)(ws + ((size_t)4 << 20));
  u16* w1p   = (u16*)(ws + ((size_t)5 << 20));   // [2][32768]
  u16* w2p   = w1p   + 65536;                    // [2][32768]
  u16* d2w1t = w2p   + 65536;                    // [2][256][256]
  u16* d2w2t = d2w1t + 131072;                   // [2][256][128]
  u16* wqt   = d2w2t + 65536;                    // [2][128][128]
  u16* wkt   = wqt   + 32768;                    // [2][128][128]

  k_pack<<<dim3(1536), 256, 0, stream>>>(ps_w1, ps_w2, d2p_w1, d2p_w2, wq, wk,
                                         w1p, w2p, d2w1t, d2w2t, wqt, wkt);

  for (int g = 0; g < 2; ++g) {
    const float* vpc = g ? (const float*)vp1 : vp_in;
    float* vpn = g ? vp_out : vp1;
    float* eps_g  = eps_base + (size_t)g * 262144;
    float* sims_g = sims_base + (size_t)g * 262144;
    const float* epprev = g ? eps_base : ep_in;

    k_point_sim<<<dim3(1152), 256, 0, stream>>>(vpc,
        w1p + (size_t)g * 32768, w2p + (size_t)g * 32768,
        ps_g1 + g * 256, ps_b1 + g * 256,
        ps_g2 + g * 128, ps_b2 + g * 128,
        ps_w3 + g * 128, ps_b3 + g, s_buf, sims_g);
    if (g) k_rank<<<dim3(2048), 128, 0, stream>>>(s_buf, epprev, maskb);
    k_edge<<<dim3(2048), 128, 0, stream>>>(s_buf, epprev, maskb, g, eps_g);
    k_qk<<<dim3(2048), 256, 0, stream>>>(vpc, wqt + (size_t)g * 16384, wkt + (size_t)g * 16384, qb, kb);
    k_attn_d2p<<<dim3(2048), 256, 0, stream>>>(qb, kb, eps_g, vpc,
        d2w1t + (size_t)g * 65536, d2p_g1 + g * 256, d2p_b1 + g * 256,
        d2w2t + (size_t)g * 32768, d2p_g2 + g * 128, d2p_b2 + g * 128, vpn);
  }
}

// Round 3
// 173.486 us; speedup vs baseline: 1.9634x; 1.3011x over previous
//
#include <hip/hip_runtime.h>
#include <hip/hip_bf16.h>

typedef unsigned int u32;
typedef unsigned short u16;
typedef float f32x4 __attribute__((ext_vector_type(4)));
typedef float f32x16 __attribute__((ext_vector_type(16)));
typedef short bh8 __attribute__((ext_vector_type(8)));   // 8 bf16 operand frag

#define NB 16
#define NN 128
#define DD 128

__device__ __forceinline__ u16 f2bf(float f) {
  union { float f; u32 u; } x; x.f = f;
  u32 r = (x.u + 0x7fffu + ((x.u >> 16) & 1u)) >> 16;
  return (u16)r;
}
__device__ __forceinline__ float bf2f(u16 h) {
  union { u32 u; float f; } x; x.u = ((u32)h) << 16;
  return x.f;
}
__device__ __forceinline__ float lrelu(float x) { return x >= 0.f ? x : 0.01f * x; }
__device__ __forceinline__ f32x16 zero16() {
  f32x16 v;
  #pragma unroll
  for (int r = 0; r < 16; ++r) v[r] = 0.f;
  return v;
}

// ---------------- unified weight pack/convert ----------------
// seg0 w1p  (65536): point-sim W1 A-frags (round-2 verified layout)
// seg1 w2p  (65536): point-sim W2 A-frags
// seg2 wqA  (32768): wq A-frags  [g][ot(4)][ks(8)][lane][r]
// seg3 wkA  (32768): wk A-frags
// seg4 w1A (131072): d2p W1 A-frags [g][ot(8)][ks(16)][lane][r]
// seg5 w2A  (65536): d2p W2 A-frags [g][ot(4)][ks(16)][lane][r]
__global__ void k_pack(const float* __restrict__ ps_w1, const float* __restrict__ ps_w2,
                       const float* __restrict__ d2p_w1, const float* __restrict__ d2p_w2,
                       const float* __restrict__ wq, const float* __restrict__ wk,
                       u16* __restrict__ w1p, u16* __restrict__ w2p,
                       u16* __restrict__ wqA, u16* __restrict__ wkA,
                       u16* __restrict__ w1A, u16* __restrict__ w2A)
{
  int idx = blockIdx.x * 256 + threadIdx.x;
  if (idx < 65536) {
    int r = idx & 7, lane = (idx >> 3) & 63, f = (idx >> 9) & 63, g = idx >> 15;
    int ct = f >> 3, ks = f & 7;
    int c = ct * 32 + (lane & 31), d = ks * 16 + (lane >> 5) * 8 + r;
    w1p[idx] = f2bf(ps_w1[(size_t)g * 32768 + c * 128 + d]);
    return;
  }
  idx -= 65536;
  if (idx < 65536) {
    int r = idx & 7, lane = (idx >> 3) & 63, f = (idx >> 9) & 63, g = idx >> 15;
    int et = f >> 4, ks2 = f & 15;
    int e = et * 32 + (lane & 31), c = ks2 * 16 + (lane >> 5) * 8 + r;
    w2p[idx] = f2bf(ps_w2[(size_t)g * 32768 + e * 256 + c]);
    return;
  }
  idx -= 65536;
  if (idx < 32768) {
    int r = idx & 7, lane = (idx >> 3) & 63, ks = (idx >> 9) & 7, ot = (idx >> 12) & 3, g = idx >> 14;
    int o = ot * 32 + (lane & 31), d = ks * 16 + (lane >> 5) * 8 + r;
    wqA[idx] = f2bf(wq[(size_t)g * 16384 + o * 128 + d]);
    return;
  }
  idx -= 32768;
  if (idx < 32768) {
    int r = idx & 7, lane = (idx >> 3) & 63, ks = (idx >> 9) & 7, ot = (idx >> 12) & 3, g = idx >> 14;
    int o = ot * 32 + (lane & 31), d = ks * 16 + (lane >> 5) * 8 + r;
    wkA[idx] = f2bf(wk[(size_t)g * 16384 + o * 128 + d]);
    return;
  }
  idx -= 32768;
  if (idx < 131072) {
    int r = idx & 7, lane = (idx >> 3) & 63, ks = (idx >> 9) & 15, ot = (idx >> 13) & 7, g = idx >> 16;
    int o = ot * 32 + (lane & 31), q = ks * 16 + (lane >> 5) * 8 + r;
    w1A[idx] = f2bf(d2p_w1[(size_t)g * 65536 + o * 256 + q]);
    return;
  }
  idx -= 131072;
  if (idx < 65536) {
    int r = idx & 7, lane = (idx >> 3) & 63, ks = (idx >> 9) & 15, ot = (idx >> 13) & 3, g = idx >> 15;
    int o = ot * 32 + (lane & 31), q = ks * 16 + (lane >> 5) * 8 + r;
    w2A[idx] = f2bf(d2p_w2[(size_t)g * 32768 + o * 256 + q]);
    return;
  }
}

// ---------------- point-sim fused MLP, tile-pair blocks, 32x32x16 MFMA ----------------
__global__ __launch_bounds__(256, 2)
void k_point_sim(const float* __restrict__ vp,
                 const u16* __restrict__ w1p, const u16* __restrict__ w2p,
                 const float* __restrict__ g1v, const float* __restrict__ b1v,
                 const float* __restrict__ g2v, const float* __restrict__ b2v,
                 const float* __restrict__ w3v, const float* __restrict__ b3v,
                 float* __restrict__ s_out, float* __restrict__ sims_out)
{
  const int bid = blockIdx.x;
  const int half = bid & 1;
  int rem = (bid >> 1) % 36;
  const int b = (bid >> 1) / 36;
  int ti = 0;
  while (rem >= 8 - ti) { rem -= 8 - ti; ++ti; }
  const int tj = ti + rem;

  const int t = threadIdx.x;
  const int lane = t & 63;
  const int w = t >> 6;
  const int p_l = lane & 31;
  const int hi = lane >> 5;
  const float rsbn = rsqrtf(1.0f + 1e-5f);

  __shared__ u16 Adiff[32 * 128];
  __shared__ u16 HL[32 * 256];
  __shared__ float sc1[256], bb1[256];
  __shared__ float sc2[128], bb2[128], w3s[128];
  __shared__ float sred[4][32];

  sc1[t] = g1v[t] * rsbn; bb1[t] = b1v[t];
  if (t < 128) { sc2[t] = g2v[t] * rsbn; bb2[t] = b2v[t]; w3s[t] = w3v[t]; }

  bh8 a1[2][8];
  #pragma unroll
  for (int c2 = 0; c2 < 2; ++c2)
    #pragma unroll
    for (int ks = 0; ks < 8; ++ks)
      a1[c2][ks] = *(const bh8*)(w1p + (((w * 2 + c2) * 8 + ks) * 64 + lane) * 8);
  bh8 a2[16];
  #pragma unroll
  for (int ks = 0; ks < 16; ++ks)
    a2[ks] = *(const bh8*)(w2p + ((w * 16 + ks) * 64 + lane) * 8);

  const int mtA = half * 4;
  const float* vpb = vp + (size_t)b * NN * DD;

  auto diffgen = [&](int mt) {
    int p = t >> 3, dseg = t & 7;
    int il = mt * 2 + (p >> 4), jl = p & 15;
    int i = ti * 16 + il, j = tj * 16 + jl;
    const float4* vi = (const float4*)(vpb + i * DD + dseg * 16);
    const float4* vj = (const float4*)(vpb + j * DD + dseg * 16);
    float rs = 0.f;
    u32 pw[8];
    #pragma unroll
    for (int c = 0; c < 4; ++c) {
      float4 av = vi[c], bv = vj[c];
      float d0 = av.x - bv.x; d0 *= d0;
      float d1 = av.y - bv.y; d1 *= d1;
      float d2 = av.z - bv.z; d2 *= d2;
      float d3 = av.w - bv.w; d3 *= d3;
      rs += d0 + d1 + d2 + d3;
      pw[c * 2]     = (u32)f2bf(d0) | ((u32)f2bf(d1) << 16);
      pw[c * 2 + 1] = (u32)f2bf(d2) | ((u32)f2bf(d3) << 16);
    }
    int base = p * 256;
    int off0 = (dseg * 32) ^ ((p & 15) << 4);
    int off1 = (dseg * 32 + 16) ^ ((p & 15) << 4);
    uint4 q0; q0.x = pw[0]; q0.y = pw[1]; q0.z = pw[2]; q0.w = pw[3];
    uint4 q1; q1.x = pw[4]; q1.y = pw[5]; q1.z = pw[6]; q1.w = pw[7];
    *(uint4*)((char*)Adiff + base + off0) = q0;
    *(uint4*)((char*)Adiff + base + off1) = q1;
    rs += __shfl_xor(rs, 1);
    rs += __shfl_xor(rs, 2);
    rs += __shfl_xor(rs, 4);
    if ((t & 7) == 0) {
      sims_out[(size_t)(b * NN + i) * NN + j] = -rs;
      if (ti != tj) sims_out[(size_t)(b * NN + j) * NN + i] = -rs;
    }
  };

  auto s_final = [&](int mt) {
    if (t < 32) {
      float z = sred[0][t] + sred[1][t] + sred[2][t] + sred[3][t] + b3v[0];
      float sv = 1.f / (1.f + __expf(-z));
      int P = mt * 32 + t;
      int il = P >> 4, jl = P & 15;
      int i = ti * 16 + il, j = tj * 16 + jl;
      s_out[(size_t)(b * NN + i) * NN + j] = sv;
      if (ti != tj) s_out[(size_t)(b * NN + j) * NN + i] = sv;
    }
  };

  diffgen(mtA);
  __syncthreads();

  for (int m = 0; m < 4; ++m) {
    const int mt = mtA + m;
    if (m > 0) s_final(mt - 1);

    f32x16 acc1[2];
    acc1[0] = zero16(); acc1[1] = zero16();
    #pragma unroll
    for (int ks = 0; ks < 8; ++ks) {
      int byte = p_l * 256 + ((ks * 32 + hi * 16) ^ ((p_l & 15) << 4));
      bh8 bf = *(const bh8*)((const char*)Adiff + byte);
      acc1[0] = __builtin_amdgcn_mfma_f32_32x32x16_bf16(a1[0][ks], bf, acc1[0], 0, 0, 0);
      acc1[1] = __builtin_amdgcn_mfma_f32_32x32x16_bf16(a1[1][ks], bf, acc1[1], 0, 0, 0);
    }
    #pragma unroll
    for (int c2 = 0; c2 < 2; ++c2) {
      #pragma unroll
      for (int g4 = 0; g4 < 4; ++g4) {
        int c0 = (w * 2 + c2) * 32 + g4 * 8 + hi * 4;
        float v0 = lrelu(acc1[c2][g4 * 4 + 0] * sc1[c0 + 0] + bb1[c0 + 0]);
        float v1 = lrelu(acc1[c2][g4 * 4 + 1] * sc1[c0 + 1] + bb1[c0 + 1]);
        float v2 = lrelu(acc1[c2][g4 * 4 + 2] * sc1[c0 + 2] + bb1[c0 + 2]);
        float v3 = lrelu(acc1[c2][g4 * 4 + 3] * sc1[c0 + 3] + bb1[c0 + 3]);
        uint2 pk;
        pk.x = (u32)f2bf(v0) | ((u32)f2bf(v1) << 16);
        pk.y = (u32)f2bf(v2) | ((u32)f2bf(v3) << 16);
        int byte = p_l * 512 + ((c0 * 2) ^ (p_l << 4));
        *(uint2*)((char*)HL + byte) = pk;
      }
    }
    __syncthreads();

    if (m < 3) diffgen(mt + 1);

    f32x16 acc2 = zero16();
    #pragma unroll
    for (int ks2 = 0; ks2 < 16; ++ks2) {
      int byte = p_l * 512 + ((ks2 * 32 + hi * 16) ^ (p_l << 4));
      bh8 bf = *(const bh8*)((const char*)HL + byte);
      acc2 = __builtin_amdgcn_mfma_f32_32x32x16_bf16(a2[ks2], bf, acc2, 0, 0, 0);
    }
    {
      float psum = 0.f;
      #pragma unroll
      for (int r = 0; r < 16; ++r) {
        int e = w * 32 + (r & 3) + 8 * (r >> 2) + 4 * hi;
        float v = lrelu(acc2[r] * sc2[e] + bb2[e]);
        psum += v * w3s[e];
      }
      psum += __shfl_xor(psum, 32);
      if (hi == 0) sred[w][p_l] = psum;
    }
    __syncthreads();
  }
  s_final(mtA + 3);
}

// ---------------- top-k rank scatter ----------------
__global__ void k_rank(const float* __restrict__ s_buf, const float* __restrict__ ep_prev,
                       float* __restrict__ mask)
{
  const int b = blockIdx.x >> 7, n = blockIdx.x & 127, t = threadIdx.x;
  __shared__ float ev[NN];
  size_t row = (size_t)(b * NN + n) * NN;
  float v = s_buf[row + t] * ((t == n) ? 0.f : ep_prev[row + t]);
  ev[t] = v;
  __syncthreads();
  int r = 0;
  for (int j = 0; j < NN; ++j) {
    float vj = ev[j];
    r += (vj > v) || (vj == v && j < t);
  }
  if (r < 115) mask[(size_t)(b * NN + t) * NN + r] = 1.0f;
}

// ---------------- edge normalization ----------------
__global__ void k_edge(const float* __restrict__ s_buf, const float* __restrict__ ep_prev,
                       float* __restrict__ maskb, int use_mask,
                       float* __restrict__ eps_out)
{
  const int b = blockIdx.x >> 7, i = blockIdx.x & 127, t = threadIdx.x;
  const int w = t >> 6, lane = t & 63;
  __shared__ float red[2][2];
  __shared__ float red2[2];
  size_t row = (size_t)(b * NN + i) * NN;
  float ep0 = (t == i) ? 0.f : ep_prev[row + t];
  float e = s_buf[row + t] * ep0;
  if (use_mask) e *= maskb[row + t];
  else maskb[(size_t)blockIdx.x * 128 + t] = 0.f;
  float a = ep0, c = fabsf(e);
  #pragma unroll
  for (int o = 32; o; o >>= 1) { a += __shfl_xor(a, o); c += __shfl_xor(c, o); }
  if (lane == 0) { red[w][0] = a; red[w][1] = c; }
  __syncthreads();
  float epsum = red[0][0] + red[1][0];
  float l1 = red[0][1] + red[1][1];
  e = e / fmaxf(l1, 1e-12f) * epsum;
  e += ((t == i) ? 1.f : 0.f) + 1e-6f;
  float d = e;
  #pragma unroll
  for (int o = 32; o; o >>= 1) d += __shfl_xor(d, o);
  if (lane == 0) red2[w] = d;
  __syncthreads();
  eps_out[row + t] = e / (red2[0] + red2[1]);
}

// ---------------- fused tail: qk proj + attn + fuse + l1 + aggr + d2p MLP ----------------
// one block per batch b; 512 threads (8 waves); 128KB dynamic LDS
__global__ __launch_bounds__(512, 1)
void k_tail(const float* __restrict__ vp, const float* __restrict__ eps_g,
            const u16* __restrict__ wqA, const u16* __restrict__ wkA,
            const u16* __restrict__ w1A, const float* __restrict__ g1v, const float* __restrict__ b1v,
            const u16* __restrict__ w2A, const float* __restrict__ g2v, const float* __restrict__ b2v,
            float* __restrict__ vpn)
{
  extern __shared__ char smem[];
  u16* VP   = (u16*)(smem);              // [128][128] bf16 row-major swz   (whole kernel)
  u16* VPT  = (u16*)(smem + 32 * 1024);  // [d][j] bf16 swz   -> later H1B
  u16* Q    = (u16*)(smem + 64 * 1024);  // q [n][o]          -> ATTP -> AGB
  u16* K    = (u16*)(smem + 96 * 1024);  // k [n][o]          -> EFN -> H1A
  u16* ATTP = Q;
  u16* AGB  = Q;
  u16* EFN  = K;
  u16* H1A  = K;
  u16* H1B  = VPT;

  const int b = blockIdx.x;
  const int t = threadIdx.x;
  const int w = t >> 6;
  const int lane = t & 63;
  const int l31 = lane & 31;
  const int hi = lane >> 5;
  const float rsbn = rsqrtf(1.f + 1e-5f);
  const float* vpb = vp + (size_t)b * NN * DD;

  // ---- P0: global fp32 -> VP (row-major bf16) + VPT (transposed bf16) ----
  {
    int rg = t >> 5;       // rows rg*8..+8
    int cg = t & 31;       // cols cg*4..+4
    float v[8][4];
    #pragma unroll
    for (int rr = 0; rr < 8; ++rr) {
      float4 a = *(const float4*)(vpb + (rg * 8 + rr) * 128 + cg * 4);
      v[rr][0] = a.x; v[rr][1] = a.y; v[rr][2] = a.z; v[rr][3] = a.w;
    }
    #pragma unroll
    for (int rr = 0; rr < 8; ++rr) {
      int row = rg * 8 + rr;
      uint2 pk;
      pk.x = (u32)f2bf(v[rr][0]) | ((u32)f2bf(v[rr][1]) << 16);
      pk.y = (u32)f2bf(v[rr][2]) | ((u32)f2bf(v[rr][3]) << 16);
      *(uint2*)((char*)VP + row * 256 + ((cg * 8) ^ ((row & 15) << 4))) = pk;
    }
    #pragma unroll
    for (int cc = 0; cc < 4; ++cc) {
      int col = cg * 4 + cc;
      uint4 pk;
      pk.x = (u32)f2bf(v[0][cc]) | ((u32)f2bf(v[1][cc]) << 16);
      pk.y = (u32)f2bf(v[2][cc]) | ((u32)f2bf(v[3][cc]) << 16);
      pk.z = (u32)f2bf(v[4][cc]) | ((u32)f2bf(v[5][cc]) << 16);
      pk.w = (u32)f2bf(v[6][cc]) | ((u32)f2bf(v[7][cc]) << 16);
      *(uint4*)((char*)VPT + col * 256 + ((rg * 16) ^ ((col & 15) << 4))) = pk;
    }
  }
  __syncthreads();   // B1

  // ---- P1: q/k projection: C[o][n] = sum_d wX[o][d] vp[n][d] ----
  {
    const int isK = w >> 2;
    const int ot = w & 3;
    const u16* WA = (isK ? wkA : wqA) + (size_t)ot * 8 * 512;
    bh8 af[8];
    #pragma unroll
    for (int ks = 0; ks < 8; ++ks) af[ks] = *(const bh8*)(WA + ks * 512 + lane * 8);
    f32x16 acc[4];
    #pragma unroll
    for (int nt = 0; nt < 4; ++nt) acc[nt] = zero16();
    #pragma unroll
    for (int nt = 0; nt < 4; ++nt) {
      int n = nt * 32 + l31;
      #pragma unroll
      for (int ks = 0; ks < 8; ++ks) {
        bh8 bf = *(const bh8*)((char*)VP + n * 256 + (((ks * 32) + hi * 16) ^ ((n & 15) << 4)));
        acc[nt] = __builtin_amdgcn_mfma_f32_32x32x16_bf16(af[ks], bf, acc[nt], 0, 0, 0);
      }
    }
    u16* DST = isK ? K : Q;
    #pragma unroll
    for (int nt = 0; nt < 4; ++nt) {
      int n = nt * 32 + l31;
      #pragma unroll
      for (int q4 = 0; q4 < 4; ++q4) {
        int o0 = ot * 32 + q4 * 8 + hi * 4;
        uint2 pk;
        pk.x = (u32)f2bf(acc[nt][q4 * 4 + 0]) | ((u32)f2bf(acc[nt][q4 * 4 + 1]) << 16);
        pk.y = (u32)f2bf(acc[nt][q4 * 4 + 2]) | ((u32)f2bf(acc[nt][q4 * 4 + 3]) << 16);
        *(uint2*)((char*)DST + n * 256 + ((o0 * 2) ^ ((n & 15) << 4))) = pk;
      }
    }
  }
  __syncthreads();   // B2

  // ---- P2: logits per head (C[j][i]), in-lane softmax, head-mean ----
  float attn[64];
  #pragma unroll
  for (int z = 0; z < 64; ++z) attn[z] = 0.f;
  const int it = w >> 1;
  const int hg = w & 1;
  const int iq = it * 32 + l31;
  {
    #pragma unroll
    for (int h4 = 0; h4 < 4; ++h4) {
      int h = hg * 4 + h4;
      bh8 qf = *(const bh8*)((char*)Q + iq * 256 + (((h * 32) + hi * 16) ^ ((iq & 15) << 4)));
      f32x16 lg[4];
      #pragma unroll
      for (int jt = 0; jt < 4; ++jt) {
        int j = jt * 32 + l31;
        bh8 kf = *(const bh8*)((char*)K + j * 256 + (((h * 32) + hi * 16) ^ ((j & 15) << 4)));
        f32x16 zz = zero16();
        lg[jt] = __builtin_amdgcn_mfma_f32_32x32x16_bf16(kf, qf, zz, 0, 0, 0);
      }
      float m = lg[0][0];
      #pragma unroll
      for (int jt = 0; jt < 4; ++jt)
        #pragma unroll
        for (int r = 0; r < 16; ++r) m = fmaxf(m, lg[jt][r]);
      m = fmaxf(m, __shfl_xor(m, 32));
      float sum = 0.f;
      #pragma unroll
      for (int jt = 0; jt < 4; ++jt)
        #pragma unroll
        for (int r = 0; r < 16; ++r) {
          float e = __expf((lg[jt][r] - m) * 0.25f);
          lg[jt][r] = e;
          sum += e;
        }
      sum += __shfl_xor(sum, 32);
      float inv = 1.f / sum;
      #pragma unroll
      for (int jt = 0; jt < 4; ++jt)
        #pragma unroll
        for (int r = 0; r < 16; ++r) attn[jt * 16 + r] += lg[jt][r] * inv;
    }
  }
  __syncthreads();   // B3 (Q/K reads done; ATTP overwrites them)

  if (hg) {
    #pragma unroll
    for (int jt = 0; jt < 4; ++jt)
      #pragma unroll
      for (int q4 = 0; q4 < 4; ++q4) {
        int j0 = jt * 32 + q4 * 8 + hi * 4;
        uint2 pk;
        pk.x = (u32)f2bf(attn[jt * 16 + q4 * 4 + 0]) | ((u32)f2bf(attn[jt * 16 + q4 * 4 + 1]) << 16);
        pk.y = (u32)f2bf(attn[jt * 16 + q4 * 4 + 2]) | ((u32)f2bf(attn[jt * 16 + q4 * 4 + 3]) << 16);
        *(uint2*)((char*)ATTP + iq * 256 + ((j0 * 2) ^ ((iq & 15) << 4))) = pk;
      }
  }
  __syncthreads();   // B4

  if (!hg) {
    #pragma unroll
    for (int jt = 0; jt < 4; ++jt)
      #pragma unroll
      for (int q4 = 0; q4 < 4; ++q4) {
        int j0 = jt * 32 + q4 * 8 + hi * 4;
        uint2 v = *(const uint2*)((char*)ATTP + iq * 256 + ((j0 * 2) ^ ((iq & 15) << 4)));
        attn[jt * 16 + q4 * 4 + 0] += bf2f((u16)(v.x & 0xffff));
        attn[jt * 16 + q4 * 4 + 1] += bf2f((u16)(v.x >> 16));
        attn[jt * 16 + q4 * 4 + 2] += bf2f((u16)(v.y & 0xffff));
        attn[jt * 16 + q4 * 4 + 3] += bf2f((u16)(v.y >> 16));
      }
    // fuse with eps, zero diag, l1-normalize over j
    const float* erow = eps_g + ((size_t)b * 128 + iq) * 128;
    float s = 0.f;
    #pragma unroll
    for (int jt = 0; jt < 4; ++jt)
      #pragma unroll
      for (int q4 = 0; q4 < 4; ++q4) {
        int j0 = jt * 32 + q4 * 8 + hi * 4;
        float4 ev = *(const float4*)(erow + j0);
        float e0 = ev.x, e1 = ev.y, e2 = ev.z, e3 = ev.w;
        float f0 = 0.5f * (e0 + attn[jt * 16 + q4 * 4 + 0] * 0.125f);
        float f1 = 0.5f * (e1 + attn[jt * 16 + q4 * 4 + 1] * 0.125f);
        float f2 = 0.5f * (e2 + attn[jt * 16 + q4 * 4 + 2] * 0.125f);
        float f3 = 0.5f * (e3 + attn[jt * 16 + q4 * 4 + 3] * 0.125f);
        if (j0 + 0 == iq) f0 = 0.f;
        if (j0 + 1 == iq) f1 = 0.f;
        if (j0 + 2 == iq) f2 = 0.f;
        if (j0 + 3 == iq) f3 = 0.f;
        attn[jt * 16 + q4 * 4 + 0] = f0;
        attn[jt * 16 + q4 * 4 + 1] = f1;
        attn[jt * 16 + q4 * 4 + 2] = f2;
        attn[jt * 16 + q4 * 4 + 3] = f3;
        s += fabsf(f0) + fabsf(f1) + fabsf(f2) + fabsf(f3);
      }
    s += __shfl_xor(s, 32);
    float inv = 1.f / fmaxf(s, 1e-12f);
    #pragma unroll
    for (int jt = 0; jt < 4; ++jt)
      #pragma unroll
      for (int q4 = 0; q4 < 4; ++q4) {
        int j0 = jt * 32 + q4 * 8 + hi * 4;
        uint2 pk;
        pk.x = (u32)f2bf(attn[jt * 16 + q4 * 4 + 0] * inv) | ((u32)f2bf(attn[jt * 16 + q4 * 4 + 1] * inv) << 16);
        pk.y = (u32)f2bf(attn[jt * 16 + q4 * 4 + 2] * inv) | ((u32)f2bf(attn[jt * 16 + q4 * 4 + 3] * inv) << 16);
        *(uint2*)((char*)EFN + iq * 256 + ((j0 * 2) ^ ((iq & 15) << 4))) = pk;
      }
  }
  __syncthreads();   // B5

  // ---- P3: aggr: C[d][i] = sum_j vpT[d][j] efn[i][j] ----
  {
    const int dt = w >> 1;
    const int ipb = (w & 1) * 2;
    bh8 af[8];
    #pragma unroll
    for (int ks = 0; ks < 8; ++ks) {
      int d = dt * 32 + l31;
      af[ks] = *(const bh8*)((char*)VPT + d * 256 + (((ks * 32) + hi * 16) ^ ((d & 15) << 4)));
    }
    f32x16 acc[2];
    acc[0] = zero16(); acc[1] = zero16();
    #pragma unroll
    for (int ii = 0; ii < 2; ++ii) {
      int i = (ipb + ii) * 32 + l31;
      #pragma unroll
      for (int ks = 0; ks < 8; ++ks) {
        bh8 bf = *(const bh8*)((char*)EFN + i * 256 + (((ks * 32) + hi * 16) ^ ((i & 15) << 4)));
        acc[ii] = __builtin_amdgcn_mfma_f32_32x32x16_bf16(af[ks], bf, acc[ii], 0, 0, 0);
      }
    }
    #pragma unroll
    for (int ii = 0; ii < 2; ++ii) {
      int i = (ipb + ii) * 32 + l31;
      #pragma unroll
      for (int q4 = 0; q4 < 4; ++q4) {
        int d0 = dt * 32 + q4 * 8 + hi * 4;
        uint2 pk;
        pk.x = (u32)f2bf(acc[ii][q4 * 4 + 0]) | ((u32)f2bf(acc[ii][q4 * 4 + 1]) << 16);
        pk.y = (u32)f2bf(acc[ii][q4 * 4 + 2]) | ((u32)f2bf(acc[ii][q4 * 4 + 3]) << 16);
        *(uint2*)((char*)AGB + i * 256 + ((d0 * 2) ^ ((i & 15) << 4))) = pk;
      }
    }
  }
  __syncthreads();   // B6

  // ---- P4: MLP1: C[o][i] = sum_q w1[o][q] feat[i][q], feat = [vp | aggr] ----
  {
    const int op = w & 3;
    const int ip = w >> 2;
    f32x16 acc[2][2];
    acc[0][0] = zero16(); acc[0][1] = zero16();
    acc[1][0] = zero16(); acc[1][1] = zero16();
    #pragma unroll
    for (int ks = 0; ks < 16; ++ks) {
      bh8 a0 = *(const bh8*)(w1A + ((size_t)((op * 2 + 0) * 16 + ks)) * 512 + lane * 8);
      bh8 a1 = *(const bh8*)(w1A + ((size_t)((op * 2 + 1) * 16 + ks)) * 512 + lane * 8);
      #pragma unroll
      for (int ii = 0; ii < 2; ++ii) {
        int i = (ip * 2 + ii) * 32 + l31;
        const char* src = (ks < 8) ? (const char*)VP : (const char*)AGB;
        int koff = (ks & 7) * 32 + hi * 16;
        bh8 bf = *(const bh8*)(src + i * 256 + (koff ^ ((i & 15) << 4)));
        acc[0][ii] = __builtin_amdgcn_mfma_f32_32x32x16_bf16(a0, bf, acc[0][ii], 0, 0, 0);
        acc[1][ii] = __builtin_amdgcn_mfma_f32_32x32x16_bf16(a1, bf, acc[1][ii], 0, 0, 0);
      }
    }
    #pragma unroll
    for (int oo = 0; oo < 2; ++oo) {
      #pragma unroll
      for (int q4 = 0; q4 < 4; ++q4) {
        int o0 = (op * 2 + oo) * 32 + q4 * 8 + hi * 4;
        float4 gg = *(const float4*)(g1v + o0);
        float4 bb = *(const float4*)(b1v + o0);
        #pragma unroll
        for (int ii = 0; ii < 2; ++ii) {
          int i = (ip * 2 + ii) * 32 + l31;
          float v0 = lrelu(acc[oo][ii][q4 * 4 + 0] * (gg.x * rsbn) + bb.x);
          float v1 = lrelu(acc[oo][ii][q4 * 4 + 1] * (gg.y * rsbn) + bb.y);
          float v2 = lrelu(acc[oo][ii][q4 * 4 + 2] * (gg.z * rsbn) + bb.z);
          float v3 = lrelu(acc[oo][ii][q4 * 4 + 3] * (gg.w * rsbn) + bb.w);
          uint2 pk;
          pk.x = (u32)f2bf(v0) | ((u32)f2bf(v1) << 16);
          pk.y = (u32)f2bf(v2) | ((u32)f2bf(v3) << 16);
          char* dst = (o0 < 128) ? (char*)H1A : (char*)H1B;
          *(uint2*)(dst + i * 256 + ((((o0 & 127) * 2)) ^ ((i & 15) << 4))) = pk;
        }
      }
    }
  }
  __syncthreads();   // B7

  // ---- P5: MLP2: C[o2][i] = sum_q2 w2[o2][q2] h1[i][q2] -> vpn ----
  {
    const int ot = w >> 1;
    const int ipb = (w & 1) * 2;
    f32x16 acc[2];
    acc[0] = zero16(); acc[1] = zero16();
    #pragma unroll
    for (int ks = 0; ks < 16; ++ks) {
      bh8 af = *(const bh8*)(w2A + ((size_t)(ot * 16 + ks)) * 512 + lane * 8);
      #pragma unroll
      for (int ii = 0; ii < 2; ++ii) {
        int i = (ipb + ii) * 32 + l31;
        const char* src = (ks < 8) ? (const char*)H1A : (const char*)H1B;
        int koff = (ks & 7) * 32 + hi * 16;
        bh8 bf = *(const bh8*)(src + i * 256 + (koff ^ ((i & 15) << 4)));
        acc[ii] = __builtin_amdgcn_mfma_f32_32x32x16_bf16(af, bf, acc[ii], 0, 0, 0);
      }
    }
    #pragma unroll
    for (int ii = 0; ii < 2; ++ii) {
      int i = (ipb + ii) * 32 + l31;
      #pragma unroll
      for (int q4 = 0; q4 < 4; ++q4) {
        int o0 = ot * 32 + q4 * 8 + hi * 4;
        float4 gg = *(const float4*)(g2v + o0);
        float4 bb = *(const float4*)(b2v + o0);
        float4 ov;
        ov.x = lrelu(acc[ii][q4 * 4 + 0] * (gg.x * rsbn) + bb.x);
        ov.y = lrelu(acc[ii][q4 * 4 + 1] * (gg.y * rsbn) + bb.y);
        ov.z = lrelu(acc[ii][q4 * 4 + 2] * (gg.z * rsbn) + bb.z);
        ov.w = lrelu(acc[ii][q4 * 4 + 3] * (gg.w * rsbn) + bb.w);
        *(float4*)(vpn + ((size_t)b * 128 + i) * 128 + o0) = ov;
      }
    }
  }
}

extern "C" void kernel_launch(void* const* d_in, const int* in_sizes, int n_in,
                              void* d_out, int out_size, void* d_ws, size_t ws_size,
                              hipStream_t stream)
{
  (void)in_sizes; (void)n_in; (void)out_size; (void)ws_size;
  const float* vp_in  = (const float*)d_in[0];
  const float* ep_in  = (const float*)d_in[1];
  const float* ps_w1  = (const float*)d_in[2];
  const float* ps_g1  = (const float*)d_in[3];
  const float* ps_b1  = (const float*)d_in[4];
  const float* ps_w2  = (const float*)d_in[5];
  const float* ps_g2  = (const float*)d_in[6];
  const float* ps_b2  = (const float*)d_in[7];
  const float* ps_w3  = (const float*)d_in[8];
  const float* ps_b3  = (const float*)d_in[9];
  const float* d2p_w1 = (const float*)d_in[10];
  const float* d2p_g1 = (const float*)d_in[11];
  const float* d2p_b1 = (const float*)d_in[12];
  const float* d2p_w2 = (const float*)d_in[13];
  const float* d2p_g2 = (const float*)d_in[14];
  const float* d2p_b2 = (const float*)d_in[15];
  const float* wq     = (const float*)d_in[16];
  const float* wk     = (const float*)d_in[17];

  float* out = (float*)d_out;
  float* eps_base  = out;                 // [2][16][128][128]
  float* sims_base = out + 524288;        // [2][16][128][128]
  float* vp_out    = out + 1048576;       // [16][128][128]

  char* ws = (char*)d_ws;
  float* s_buf = (float*)(ws + ((size_t)0 << 20));
  float* maskb = (float*)(ws + ((size_t)1 << 20));
  float* vp1   = (float*)(ws + ((size_t)2 << 20));
  u16* w1p = (u16*)(ws + ((size_t)3 << 20));
  u16* w2p = w1p + 65536;
  u16* wqA = w2p + 65536;      // [g][4][8][512]
  u16* wkA = wqA + 32768;
  u16* w1A = wkA + 32768;      // [g][8][16][512]
  u16* w2A = w1A + 131072;     // [g][4][16][512]

  k_pack<<<dim3(1536), 256, 0, stream>>>(ps_w1, ps_w2, d2p_w1, d2p_w2, wq, wk,
                                         w1p, w2p, wqA, wkA, w1A, w2A);

  hipFuncSetAttribute((const void*)k_tail, hipFuncAttributeMaxDynamicSharedMemorySize, 131072);

  for (int g = 0; g < 2; ++g) {
    const float* vpc = g ? (const float*)vp1 : vp_in;
    float* vpn = g ? vp_out : vp1;
    float* eps_g  = eps_base + (size_t)g * 262144;
    float* sims_g = sims_base + (size_t)g * 262144;
    const float* epprev = g ? eps_base : ep_in;

    k_point_sim<<<dim3(1152), 256, 0, stream>>>(vpc,
        w1p + (size_t)g * 32768, w2p + (size_t)g * 32768,
        ps_g1 + g * 256, ps_b1 + g * 256,
        ps_g2 + g * 128, ps_b2 + g * 128,
        ps_w3 + g * 128, ps_b3 + g, s_buf, sims_g);
    if (g) k_rank<<<dim3(2048), 128, 0, stream>>>(s_buf, epprev, maskb);
    k_edge<<<dim3(2048), 128, 0, stream>>>(s_buf, epprev, maskb, g, eps_g);
    k_tail<<<dim3(16), 512, 131072, stream>>>(vpc, eps_g,
        wqA + (size_t)g * 16384, wkA + (size_t)g * 16384,
        w1A + (size_t)g * 65536, d2p_g1 + g * 256, d2p_b1 + g * 256,
        w2A + (size_t)g * 32768, d2p_g2 + g * 128, d2p_b2 + g * 128, vpn);
  }
}

// Round 4
// 150.677 us; speedup vs baseline: 2.2606x; 1.1514x over previous
//
#include <hip/hip_runtime.h>
#include <hip/hip_bf16.h>

typedef unsigned int u32;
typedef unsigned short u16;
typedef float f32x4 __attribute__((ext_vector_type(4)));
typedef float f32x16 __attribute__((ext_vector_type(16)));
typedef short bh8 __attribute__((ext_vector_type(8)));   // 8 bf16 operand frag

#define NB 16
#define NN 128
#define DD 128

__device__ __forceinline__ u16 f2bf(float f) {
  union { float f; u32 u; } x; x.f = f;
  u32 r = (x.u + 0x7fffu + ((x.u >> 16) & 1u)) >> 16;
  return (u16)r;
}
__device__ __forceinline__ float bf2f(u16 h) {
  union { u32 u; float f; } x; x.u = ((u32)h) << 16;
  return x.f;
}
__device__ __forceinline__ float lrelu(float x) { return x >= 0.f ? x : 0.01f * x; }
__device__ __forceinline__ f32x16 zero16() {
  f32x16 v;
  #pragma unroll
  for (int r = 0; r < 16; ++r) v[r] = 0.f;
  return v;
}

// ---------------- unified weight pack/convert ----------------
__global__ void k_pack(const float* __restrict__ ps_w1, const float* __restrict__ ps_w2,
                       const float* __restrict__ d2p_w1, const float* __restrict__ d2p_w2,
                       const float* __restrict__ wq, const float* __restrict__ wk,
                       u16* __restrict__ w1p, u16* __restrict__ w2p,
                       u16* __restrict__ wqA, u16* __restrict__ wkA,
                       u16* __restrict__ w1A, u16* __restrict__ w2A)
{
  int idx = blockIdx.x * 256 + threadIdx.x;
  if (idx < 65536) {
    int r = idx & 7, lane = (idx >> 3) & 63, f = (idx >> 9) & 63, g = idx >> 15;
    int ct = f >> 3, ks = f & 7;
    int c = ct * 32 + (lane & 31), d = ks * 16 + (lane >> 5) * 8 + r;
    w1p[idx] = f2bf(ps_w1[(size_t)g * 32768 + c * 128 + d]);
    return;
  }
  idx -= 65536;
  if (idx < 65536) {
    int r = idx & 7, lane = (idx >> 3) & 63, f = (idx >> 9) & 63, g = idx >> 15;
    int et = f >> 4, ks2 = f & 15;
    int e = et * 32 + (lane & 31), c = ks2 * 16 + (lane >> 5) * 8 + r;
    w2p[idx] = f2bf(ps_w2[(size_t)g * 32768 + e * 256 + c]);
    return;
  }
  idx -= 65536;
  if (idx < 32768) {
    int r = idx & 7, lane = (idx >> 3) & 63, ks = (idx >> 9) & 7, ot = (idx >> 12) & 3, g = idx >> 14;
    int o = ot * 32 + (lane & 31), d = ks * 16 + (lane >> 5) * 8 + r;
    wqA[idx] = f2bf(wq[(size_t)g * 16384 + o * 128 + d]);
    return;
  }
  idx -= 32768;
  if (idx < 32768) {
    int r = idx & 7, lane = (idx >> 3) & 63, ks = (idx >> 9) & 7, ot = (idx >> 12) & 3, g = idx >> 14;
    int o = ot * 32 + (lane & 31), d = ks * 16 + (lane >> 5) * 8 + r;
    wkA[idx] = f2bf(wk[(size_t)g * 16384 + o * 128 + d]);
    return;
  }
  idx -= 32768;
  if (idx < 131072) {
    int r = idx & 7, lane = (idx >> 3) & 63, ks = (idx >> 9) & 15, ot = (idx >> 13) & 7, g = idx >> 16;
    int o = ot * 32 + (lane & 31), q = ks * 16 + (lane >> 5) * 8 + r;
    w1A[idx] = f2bf(d2p_w1[(size_t)g * 65536 + o * 256 + q]);
    return;
  }
  idx -= 131072;
  if (idx < 65536) {
    int r = idx & 7, lane = (idx >> 3) & 63, ks = (idx >> 9) & 15, ot = (idx >> 13) & 3, g = idx >> 15;
    int o = ot * 32 + (lane & 31), q = ks * 16 + (lane >> 5) * 8 + r;
    w2A[idx] = f2bf(d2p_w2[(size_t)g * 32768 + o * 256 + q]);
    return;
  }
}

// ---------------- point-sim fused MLP, tile-pair blocks, 32x32x16 MFMA ----------------
// All global stores buffered in LDS, emitted once at kernel end (no vmcnt store-drain
// at the per-tile barriers).
__global__ __launch_bounds__(256, 2)
void k_point_sim(const float* __restrict__ vp,
                 const u16* __restrict__ w1p, const u16* __restrict__ w2p,
                 const float* __restrict__ g1v, const float* __restrict__ b1v,
                 const float* __restrict__ g2v, const float* __restrict__ b2v,
                 const float* __restrict__ w3v, const float* __restrict__ b3v,
                 float* __restrict__ s_out, float* __restrict__ sims_out)
{
  const int bid = blockIdx.x;
  const int half = bid & 1;
  int rem = (bid >> 1) % 36;
  const int b = (bid >> 1) / 36;
  int ti = 0;
  while (rem >= 8 - ti) { rem -= 8 - ti; ++ti; }
  const int tj = ti + rem;

  const int t = threadIdx.x;
  const int lane = t & 63;
  const int w = t >> 6;
  const int p_l = lane & 31;
  const int hi = lane >> 5;
  const float rsbn = rsqrtf(1.0f + 1e-5f);

  __shared__ u16 Adiff[32 * 128];
  __shared__ u16 HL[32 * 256];
  __shared__ float sc1[256], bb1[256];
  __shared__ float sc2[128], bb2[128], w3s[128];
  __shared__ float sred[4][32];
  __shared__ float simv[128];
  __shared__ float svv[128];

  sc1[t] = g1v[t] * rsbn; bb1[t] = b1v[t];
  if (t < 128) { sc2[t] = g2v[t] * rsbn; bb2[t] = b2v[t]; w3s[t] = w3v[t]; }

  bh8 a1[2][8];
  #pragma unroll
  for (int c2 = 0; c2 < 2; ++c2)
    #pragma unroll
    for (int ks = 0; ks < 8; ++ks)
      a1[c2][ks] = *(const bh8*)(w1p + (((w * 2 + c2) * 8 + ks) * 64 + lane) * 8);
  bh8 a2[16];
  #pragma unroll
  for (int ks = 0; ks < 16; ++ks)
    a2[ks] = *(const bh8*)(w2p + ((w * 16 + ks) * 64 + lane) * 8);

  const int mtA = half * 4;
  const float* vpb = vp + (size_t)b * NN * DD;

  auto diffgen = [&](int mt) {
    int p = t >> 3, dseg = t & 7;
    int il = mt * 2 + (p >> 4), jl = p & 15;
    int i = ti * 16 + il, j = tj * 16 + jl;
    const float4* vi = (const float4*)(vpb + i * DD + dseg * 16);
    const float4* vj = (const float4*)(vpb + j * DD + dseg * 16);
    float rs = 0.f;
    u32 pw[8];
    #pragma unroll
    for (int c = 0; c < 4; ++c) {
      float4 av = vi[c], bv = vj[c];
      float d0 = av.x - bv.x; d0 *= d0;
      float d1 = av.y - bv.y; d1 *= d1;
      float d2 = av.z - bv.z; d2 *= d2;
      float d3 = av.w - bv.w; d3 *= d3;
      rs += d0 + d1 + d2 + d3;
      pw[c * 2]     = (u32)f2bf(d0) | ((u32)f2bf(d1) << 16);
      pw[c * 2 + 1] = (u32)f2bf(d2) | ((u32)f2bf(d3) << 16);
    }
    int base = p * 256;
    int off0 = (dseg * 32) ^ ((p & 15) << 4);
    int off1 = (dseg * 32 + 16) ^ ((p & 15) << 4);
    uint4 q0; q0.x = pw[0]; q0.y = pw[1]; q0.z = pw[2]; q0.w = pw[3];
    uint4 q1; q1.x = pw[4]; q1.y = pw[5]; q1.z = pw[6]; q1.w = pw[7];
    *(uint4*)((char*)Adiff + base + off0) = q0;
    *(uint4*)((char*)Adiff + base + off1) = q1;
    rs += __shfl_xor(rs, 1);
    rs += __shfl_xor(rs, 2);
    rs += __shfl_xor(rs, 4);
    if ((t & 7) == 0) simv[(mt - mtA) * 32 + p] = rs;
  };

  auto s_final = [&](int mt) {
    if (t < 32) {
      float z = sred[0][t] + sred[1][t] + sred[2][t] + sred[3][t] + b3v[0];
      svv[(mt - mtA) * 32 + t] = 1.f / (1.f + __expf(-z));
    }
  };

  diffgen(mtA);
  __syncthreads();

  for (int m = 0; m < 4; ++m) {
    const int mt = mtA + m;
    if (m > 0) s_final(mt - 1);

    f32x16 acc1[2];
    acc1[0] = zero16(); acc1[1] = zero16();
    #pragma unroll
    for (int ks = 0; ks < 8; ++ks) {
      int byte = p_l * 256 + ((ks * 32 + hi * 16) ^ ((p_l & 15) << 4));
      bh8 bf = *(const bh8*)((const char*)Adiff + byte);
      acc1[0] = __builtin_amdgcn_mfma_f32_32x32x16_bf16(a1[0][ks], bf, acc1[0], 0, 0, 0);
      acc1[1] = __builtin_amdgcn_mfma_f32_32x32x16_bf16(a1[1][ks], bf, acc1[1], 0, 0, 0);
    }
    #pragma unroll
    for (int c2 = 0; c2 < 2; ++c2) {
      #pragma unroll
      for (int g4 = 0; g4 < 4; ++g4) {
        int c0 = (w * 2 + c2) * 32 + g4 * 8 + hi * 4;
        float v0 = lrelu(acc1[c2][g4 * 4 + 0] * sc1[c0 + 0] + bb1[c0 + 0]);
        float v1 = lrelu(acc1[c2][g4 * 4 + 1] * sc1[c0 + 1] + bb1[c0 + 1]);
        float v2 = lrelu(acc1[c2][g4 * 4 + 2] * sc1[c0 + 2] + bb1[c0 + 2]);
        float v3 = lrelu(acc1[c2][g4 * 4 + 3] * sc1[c0 + 3] + bb1[c0 + 3]);
        uint2 pk;
        pk.x = (u32)f2bf(v0) | ((u32)f2bf(v1) << 16);
        pk.y = (u32)f2bf(v2) | ((u32)f2bf(v3) << 16);
        int byte = p_l * 512 + ((c0 * 2) ^ (p_l << 4));
        *(uint2*)((char*)HL + byte) = pk;
      }
    }
    __syncthreads();

    if (m < 3) diffgen(mt + 1);

    f32x16 acc2 = zero16();
    #pragma unroll
    for (int ks2 = 0; ks2 < 16; ++ks2) {
      int byte = p_l * 512 + ((ks2 * 32 + hi * 16) ^ (p_l << 4));
      bh8 bf = *(const bh8*)((const char*)HL + byte);
      acc2 = __builtin_amdgcn_mfma_f32_32x32x16_bf16(a2[ks2], bf, acc2, 0, 0, 0);
    }
    {
      float psum = 0.f;
      #pragma unroll
      for (int r = 0; r < 16; ++r) {
        int e = w * 32 + (r & 3) + 8 * (r >> 2) + 4 * hi;
        float v = lrelu(acc2[r] * sc2[e] + bb2[e]);
        psum += v * w3s[e];
      }
      psum += __shfl_xor(psum, 32);
      if (hi == 0) sred[w][p_l] = psum;
    }
    __syncthreads();
  }
  s_final(mtA + 3);
  __syncthreads();

  // write-out: all global stores at kernel end
  {
    int idx = t & 127;
    int mm = idx >> 5, pp = idx & 31;
    int mt = mtA + mm;
    int i = ti * 16 + mt * 2 + (pp >> 4);
    int j = tj * 16 + (pp & 15);
    float sv = svv[idx];
    float sm = -simv[idx];
    if (t < 128) {
      s_out[(size_t)(b * NN + i) * NN + j] = sv;
      sims_out[(size_t)(b * NN + i) * NN + j] = sm;
    } else if (ti != tj) {
      s_out[(size_t)(b * NN + j) * NN + i] = sv;
      sims_out[(size_t)(b * NN + j) * NN + i] = sm;
    }
  }
}

// ---------------- top-k rank scatter ----------------
__global__ void k_rank(const float* __restrict__ s_buf, const float* __restrict__ ep_prev,
                       float* __restrict__ mask)
{
  const int b = blockIdx.x >> 7, n = blockIdx.x & 127, t = threadIdx.x;
  __shared__ float ev[NN];
  size_t row = (size_t)(b * NN + n) * NN;
  float v = s_buf[row + t] * ((t == n) ? 0.f : ep_prev[row + t]);
  ev[t] = v;
  __syncthreads();
  int r = 0;
  for (int j = 0; j < NN; ++j) {
    float vj = ev[j];
    r += (vj > v) || (vj == v && j < t);
  }
  if (r < 115) mask[(size_t)(b * NN + t) * NN + r] = 1.0f;
}

// ---------------- edge normalization ----------------
__global__ void k_edge(const float* __restrict__ s_buf, const float* __restrict__ ep_prev,
                       float* __restrict__ maskb, int use_mask,
                       float* __restrict__ eps_out)
{
  const int b = blockIdx.x >> 7, i = blockIdx.x & 127, t = threadIdx.x;
  const int w = t >> 6, lane = t & 63;
  __shared__ float red[2][2];
  __shared__ float red2[2];
  size_t row = (size_t)(b * NN + i) * NN;
  float ep0 = (t == i) ? 0.f : ep_prev[row + t];
  float e = s_buf[row + t] * ep0;
  if (use_mask) e *= maskb[row + t];
  else maskb[(size_t)blockIdx.x * 128 + t] = 0.f;
  float a = ep0, c = fabsf(e);
  #pragma unroll
  for (int o = 32; o; o >>= 1) { a += __shfl_xor(a, o); c += __shfl_xor(c, o); }
  if (lane == 0) { red[w][0] = a; red[w][1] = c; }
  __syncthreads();
  float epsum = red[0][0] + red[1][0];
  float l1 = red[0][1] + red[1][1];
  e = e / fmaxf(l1, 1e-12f) * epsum;
  e += ((t == i) ? 1.f : 0.f) + 1e-6f;
  float d = e;
  #pragma unroll
  for (int o = 32; o; o >>= 1) d += __shfl_xor(d, o);
  if (lane == 0) red2[w] = d;
  __syncthreads();
  eps_out[row + t] = e / (red2[0] + red2[1]);
}

// ---------------- k_prep: vp -> bf16 (row + transposed) + q/k projection ----------------
// grid = 16 (one per b), 512 threads (8 waves)
__global__ __launch_bounds__(512)
void k_prep(const float* __restrict__ vp,
            const u16* __restrict__ wqA, const u16* __restrict__ wkA,
            u16* __restrict__ Qb, u16* __restrict__ Kb,
            u16* __restrict__ VPb, u16* __restrict__ VPT)
{
  __shared__ u16 VPs[128 * 128];   // 32 KB swizzled row-major
  const int b = blockIdx.x;
  const int t = threadIdx.x;
  const int w = t >> 6;
  const int lane = t & 63;
  const int l31 = lane & 31;
  const int hi = lane >> 5;
  const float* vpb = vp + (size_t)b * NN * DD;

  {
    int rg = t >> 5;        // 0..15 -> rows rg*8..+8
    int cg = t & 31;        // cols cg*4..+4
    float v[8][4];
    #pragma unroll
    for (int rr = 0; rr < 8; ++rr) {
      float4 a = *(const float4*)(vpb + (rg * 8 + rr) * 128 + cg * 4);
      v[rr][0] = a.x; v[rr][1] = a.y; v[rr][2] = a.z; v[rr][3] = a.w;
    }
    #pragma unroll
    for (int rr = 0; rr < 8; ++rr) {
      int row = rg * 8 + rr;
      uint2 pk;
      pk.x = (u32)f2bf(v[rr][0]) | ((u32)f2bf(v[rr][1]) << 16);
      pk.y = (u32)f2bf(v[rr][2]) | ((u32)f2bf(v[rr][3]) << 16);
      *(uint2*)((char*)VPs + row * 256 + ((cg * 8) ^ ((row & 15) << 4))) = pk;
      *(uint2*)(VPb + (size_t)b * 16384 + row * 128 + cg * 4) = pk;
    }
    #pragma unroll
    for (int cc = 0; cc < 4; ++cc) {
      int col = cg * 4 + cc;
      uint4 pk;
      pk.x = (u32)f2bf(v[0][cc]) | ((u32)f2bf(v[1][cc]) << 16);
      pk.y = (u32)f2bf(v[2][cc]) | ((u32)f2bf(v[3][cc]) << 16);
      pk.z = (u32)f2bf(v[4][cc]) | ((u32)f2bf(v[5][cc]) << 16);
      pk.w = (u32)f2bf(v[6][cc]) | ((u32)f2bf(v[7][cc]) << 16);
      *(uint4*)(VPT + (size_t)b * 16384 + col * 128 + rg * 8) = pk;
    }
  }
  __syncthreads();

  // q/k GEMM: C[o][n] = sum_d W[o][d] * vp[n][d]
  {
    const int isK = w >> 2;
    const int ot = w & 3;
    const u16* WA = (isK ? wkA : wqA) + (size_t)ot * 8 * 512;
    bh8 af[8];
    #pragma unroll
    for (int ks = 0; ks < 8; ++ks) af[ks] = *(const bh8*)(WA + ks * 512 + lane * 8);
    u16* DST = (isK ? Kb : Qb) + (size_t)b * 16384;
    #pragma unroll
    for (int nt = 0; nt < 4; ++nt) {
      int n = nt * 32 + l31;
      f32x16 acc = zero16();
      #pragma unroll
      for (int ks = 0; ks < 8; ++ks) {
        bh8 bf = *(const bh8*)((char*)VPs + n * 256 + (((ks * 32) + hi * 16) ^ ((n & 15) << 4)));
        acc = __builtin_amdgcn_mfma_f32_32x32x16_bf16(af[ks], bf, acc, 0, 0, 0);
      }
      #pragma unroll
      for (int q4 = 0; q4 < 4; ++q4) {
        int o0 = ot * 32 + q4 * 8 + hi * 4;
        uint2 pk;
        pk.x = (u32)f2bf(acc[q4 * 4 + 0]) | ((u32)f2bf(acc[q4 * 4 + 1]) << 16);
        pk.y = (u32)f2bf(acc[q4 * 4 + 2]) | ((u32)f2bf(acc[q4 * 4 + 3]) << 16);
        *(uint2*)(DST + n * 128 + o0) = pk;
      }
    }
  }
}

// ---------------- k_attn: per-head logits + softmax + head-mean + fuse + l1 -> EFN ----------------
// grid = 16 b * 4 i-chunks = 64 blocks, 256 threads (4 waves)
__global__ __launch_bounds__(256)
void k_attn(const u16* __restrict__ Qb, const u16* __restrict__ Kb,
            const float* __restrict__ eps_g, u16* __restrict__ EFN)
{
  __shared__ u16 att[4 * 32 * 128];   // 32 KB wave-partial bf16
  const int b = blockIdx.x >> 2;
  const int ch = blockIdx.x & 3;
  const int t = threadIdx.x;
  const int w = t >> 6;
  const int lane = t & 63;
  const int l31 = lane & 31;
  const int hi = lane >> 5;

  float asum[64];
  #pragma unroll
  for (int z = 0; z < 64; ++z) asum[z] = 0.f;

  const u16* Qrow = Qb + (size_t)b * 16384 + (ch * 32 + l31) * 128;
  #pragma unroll
  for (int hh = 0; hh < 2; ++hh) {
    int h = w * 2 + hh;
    bh8 qf = *(const bh8*)(Qrow + h * 16 + hi * 8);
    f32x16 lg[4];
    #pragma unroll
    for (int jt = 0; jt < 4; ++jt) {
      bh8 kf = *(const bh8*)(Kb + (size_t)b * 16384 + (jt * 32 + l31) * 128 + h * 16 + hi * 8);
      f32x16 zz = zero16();
      lg[jt] = __builtin_amdgcn_mfma_f32_32x32x16_bf16(kf, qf, zz, 0, 0, 0);
    }
    float m = lg[0][0];
    #pragma unroll
    for (int jt = 0; jt < 4; ++jt)
      #pragma unroll
      for (int r = 0; r < 16; ++r) m = fmaxf(m, lg[jt][r]);
    m = fmaxf(m, __shfl_xor(m, 32));
    float sum = 0.f;
    #pragma unroll
    for (int jt = 0; jt < 4; ++jt)
      #pragma unroll
      for (int r = 0; r < 16; ++r) {
        float e = __expf((lg[jt][r] - m) * 0.25f);
        lg[jt][r] = e;
        sum += e;
      }
    sum += __shfl_xor(sum, 32);
    float inv = 1.f / sum;
    #pragma unroll
    for (int jt = 0; jt < 4; ++jt)
      #pragma unroll
      for (int r = 0; r < 16; ++r) asum[jt * 16 + r] += lg[jt][r] * inv;
  }
  // write 2-head partial: att[w][i=l31][j], j-linear in 16B chunks, XOR swizzle
  #pragma unroll
  for (int jt = 0; jt < 4; ++jt)
    #pragma unroll
    for (int q4 = 0; q4 < 4; ++q4) {
      int j0 = jt * 32 + q4 * 8 + hi * 4;
      uint2 pk;
      pk.x = (u32)f2bf(asum[jt * 16 + q4 * 4 + 0]) | ((u32)f2bf(asum[jt * 16 + q4 * 4 + 1]) << 16);
      pk.y = (u32)f2bf(asum[jt * 16 + q4 * 4 + 2]) | ((u32)f2bf(asum[jt * 16 + q4 * 4 + 3]) << 16);
      *(uint2*)((char*)att + (w * 32 + l31) * 256 + ((j0 * 2) ^ ((l31 & 15) << 4))) = pk;
    }
  __syncthreads();

  // combine 4 wave-partials; fuse with eps; l1-normalize; write EFN bf16
  {
    int il = t >> 3;             // 0..31 local i
    int jseg = t & 7;            // 16 j each
    int i = ch * 32 + il;
    float a[16];
    #pragma unroll
    for (int z = 0; z < 16; ++z) a[z] = 0.f;
    #pragma unroll
    for (int ww = 0; ww < 4; ++ww) {
      #pragma unroll
      for (int c = 0; c < 2; ++c) {
        uint4 v = *(const uint4*)((char*)att + (ww * 32 + il) * 256 + (((jseg * 32) + c * 16) ^ ((il & 15) << 4)));
        u32 uu[4] = {v.x, v.y, v.z, v.w};
        #pragma unroll
        for (int k = 0; k < 4; ++k) {
          a[c * 8 + k * 2 + 0] += bf2f((u16)(uu[k] & 0xffff));
          a[c * 8 + k * 2 + 1] += bf2f((u16)(uu[k] >> 16));
        }
      }
    }
    const float* erow = eps_g + ((size_t)b * 128 + i) * 128 + jseg * 16;
    float f[16];
    float s = 0.f;
    #pragma unroll
    for (int c = 0; c < 4; ++c) {
      float4 ev = *(const float4*)(erow + c * 4);
      float e0 = ev.x, e1 = ev.y, e2 = ev.z, e3 = ev.w;
      #pragma unroll
      for (int k = 0; k < 4; ++k) {
        int jj = jseg * 16 + c * 4 + k;
        float ev1 = (k == 0) ? e0 : (k == 1) ? e1 : (k == 2) ? e2 : e3;
        float fv = 0.5f * (ev1 + a[c * 4 + k] * 0.125f);
        if (jj == i) fv = 0.f;
        f[c * 4 + k] = fv;
        s += fabsf(fv);
      }
    }
    s += __shfl_xor(s, 1);
    s += __shfl_xor(s, 2);
    s += __shfl_xor(s, 4);
    float inv = 1.f / fmaxf(s, 1e-12f);
    u16* dst = EFN + (size_t)b * 16384 + i * 128 + jseg * 16;
    uint4 o0, o1;
    u32* op = (u32*)&o0;
    #pragma unroll
    for (int k = 0; k < 4; ++k)
      op[k] = (u32)f2bf(f[k * 2 + 0] * inv) | ((u32)f2bf(f[k * 2 + 1] * inv) << 16);
    u32* op1 = (u32*)&o1;
    #pragma unroll
    for (int k = 0; k < 4; ++k)
      op1[k] = (u32)f2bf(f[8 + k * 2 + 0] * inv) | ((u32)f2bf(f[8 + k * 2 + 1] * inv) << 16);
    *(uint4*)(dst) = o0;
    *(uint4*)(dst + 8) = o1;
  }
}

// ---------------- k_d2p: aggr + MLP1 + MLP2 -> vpn ----------------
// grid = 16 b * 4 i-chunks = 64 blocks, 256 threads (4 waves)
__global__ __launch_bounds__(256)
void k_d2p(const u16* __restrict__ EFN, const u16* __restrict__ VPb, const u16* __restrict__ VPT,
           const u16* __restrict__ w1A, const float* __restrict__ g1v, const float* __restrict__ b1v,
           const u16* __restrict__ w2A, const float* __restrict__ g2v, const float* __restrict__ b2v,
           float* __restrict__ vpn)
{
  __shared__ u16 AG[32 * 128];   // 8 KB  aggr bf16 [i][d] swz
  __shared__ u16 HB[32 * 256];   // 16 KB h1   bf16 [i][o] swz
  const int b = blockIdx.x >> 2;
  const int ch = blockIdx.x & 3;
  const int t = threadIdx.x;
  const int w = t >> 6;
  const int lane = t & 63;
  const int l31 = lane & 31;
  const int hi = lane >> 5;
  const float rsbn = rsqrtf(1.f + 1e-5f);

  // P0: aggr C[d][i] = sum_j vpT[d][j] * efn[i][j]   (wave w = d-tile)
  {
    const u16* efrow = EFN + (size_t)b * 16384 + (ch * 32 + l31) * 128;
    const u16* vtrow = VPT + (size_t)b * 16384 + (w * 32 + l31) * 128;
    f32x16 acc = zero16();
    #pragma unroll
    for (int ks = 0; ks < 8; ++ks) {
      bh8 af = *(const bh8*)(vtrow + ks * 16 + hi * 8);
      bh8 bf = *(const bh8*)(efrow + ks * 16 + hi * 8);
      acc = __builtin_amdgcn_mfma_f32_32x32x16_bf16(af, bf, acc, 0, 0, 0);
    }
    #pragma unroll
    for (int q4 = 0; q4 < 4; ++q4) {
      int d0 = w * 32 + q4 * 8 + hi * 4;
      uint2 pk;
      pk.x = (u32)f2bf(acc[q4 * 4 + 0]) | ((u32)f2bf(acc[q4 * 4 + 1]) << 16);
      pk.y = (u32)f2bf(acc[q4 * 4 + 2]) | ((u32)f2bf(acc[q4 * 4 + 3]) << 16);
      *(uint2*)((char*)AG + l31 * 256 + ((d0 * 2) ^ ((l31 & 15) << 4))) = pk;
    }
  }
  __syncthreads();

  // P1: MLP1 C[o][i] = sum_q w1[o][q] feat[i][q]  (wave w = 2 o-tiles)
  {
    const u16* vprow = VPb + (size_t)b * 16384 + (ch * 32 + l31) * 128;
    f32x16 acc0 = zero16(), acc1v = zero16();
    #pragma unroll
    for (int ks = 0; ks < 16; ++ks) {
      bh8 a0 = *(const bh8*)(w1A + ((size_t)((w * 2 + 0) * 16 + ks)) * 512 + lane * 8);
      bh8 a1 = *(const bh8*)(w1A + ((size_t)((w * 2 + 1) * 16 + ks)) * 512 + lane * 8);
      bh8 bf;
      if (ks < 8) bf = *(const bh8*)(vprow + ks * 16 + hi * 8);
      else bf = *(const bh8*)((char*)AG + l31 * 256 + ((((ks - 8) * 32) + hi * 16) ^ ((l31 & 15) << 4)));
      acc0 = __builtin_amdgcn_mfma_f32_32x32x16_bf16(a0, bf, acc0, 0, 0, 0);
      acc1v = __builtin_amdgcn_mfma_f32_32x32x16_bf16(a1, bf, acc1v, 0, 0, 0);
    }
    #pragma unroll
    for (int oo = 0; oo < 2; ++oo) {
      const f32x16& acc = oo ? acc1v : acc0;
      #pragma unroll
      for (int q4 = 0; q4 < 4; ++q4) {
        int o0 = (w * 2 + oo) * 32 + q4 * 8 + hi * 4;
        float4 gg = *(const float4*)(g1v + o0);
        float4 bb = *(const float4*)(b1v + o0);
        float v0 = lrelu(acc[q4 * 4 + 0] * (gg.x * rsbn) + bb.x);
        float v1 = lrelu(acc[q4 * 4 + 1] * (gg.y * rsbn) + bb.y);
        float v2 = lrelu(acc[q4 * 4 + 2] * (gg.z * rsbn) + bb.z);
        float v3 = lrelu(acc[q4 * 4 + 3] * (gg.w * rsbn) + bb.w);
        uint2 pk;
        pk.x = (u32)f2bf(v0) | ((u32)f2bf(v1) << 16);
        pk.y = (u32)f2bf(v2) | ((u32)f2bf(v3) << 16);
        *(uint2*)((char*)HB + l31 * 512 + ((o0 * 2) ^ (l31 << 4))) = pk;
      }
    }
  }
  __syncthreads();

  // P2: MLP2 C[o2][i] = sum_q2 w2[o2][q2] h1[i][q2]  (wave w = o2-tile)
  {
    f32x16 acc = zero16();
    #pragma unroll
    for (int ks = 0; ks < 16; ++ks) {
      bh8 af = *(const bh8*)(w2A + ((size_t)(w * 16 + ks)) * 512 + lane * 8);
      bh8 bf = *(const bh8*)((char*)HB + l31 * 512 + (((ks * 32) + hi * 16) ^ (l31 << 4)));
      acc = __builtin_amdgcn_mfma_f32_32x32x16_bf16(af, bf, acc, 0, 0, 0);
    }
    int i = ch * 32 + l31;
    #pragma unroll
    for (int q4 = 0; q4 < 4; ++q4) {
      int o0 = w * 32 + q4 * 8 + hi * 4;
      float4 gg = *(const float4*)(g2v + o0);
      float4 bb = *(const float4*)(b2v + o0);
      float4 ov;
      ov.x = lrelu(acc[q4 * 4 + 0] * (gg.x * rsbn) + bb.x);
      ov.y = lrelu(acc[q4 * 4 + 1] * (gg.y * rsbn) + bb.y);
      ov.z = lrelu(acc[q4 * 4 + 2] * (gg.z * rsbn) + bb.z);
      ov.w = lrelu(acc[q4 * 4 + 3] * (gg.w * rsbn) + bb.w);
      *(float4*)(vpn + ((size_t)b * 128 + i) * 128 + o0) = ov;
    }
  }
}

extern "C" void kernel_launch(void* const* d_in, const int* in_sizes, int n_in,
                              void* d_out, int out_size, void* d_ws, size_t ws_size,
                              hipStream_t stream)
{
  (void)in_sizes; (void)n_in; (void)out_size; (void)ws_size;
  const float* vp_in  = (const float*)d_in[0];
  const float* ep_in  = (const float*)d_in[1];
  const float* ps_w1  = (const float*)d_in[2];
  const float* ps_g1  = (const float*)d_in[3];
  const float* ps_b1  = (const float*)d_in[4];
  const float* ps_w2  = (const float*)d_in[5];
  const float* ps_g2  = (const float*)d_in[6];
  const float* ps_b2  = (const float*)d_in[7];
  const float* ps_w3  = (const float*)d_in[8];
  const float* ps_b3  = (const float*)d_in[9];
  const float* d2p_w1 = (const float*)d_in[10];
  const float* d2p_g1 = (const float*)d_in[11];
  const float* d2p_b1 = (const float*)d_in[12];
  const float* d2p_w2 = (const float*)d_in[13];
  const float* d2p_g2 = (const float*)d_in[14];
  const float* d2p_b2 = (const float*)d_in[15];
  const float* wq     = (const float*)d_in[16];
  const float* wk     = (const float*)d_in[17];

  float* out = (float*)d_out;
  float* eps_base  = out;                 // [2][16][128][128]
  float* sims_base = out + 524288;        // [2][16][128][128]
  float* vp_out    = out + 1048576;       // [16][128][128]

  char* ws = (char*)d_ws;
  float* s_buf = (float*)(ws + ((size_t)0 << 20));
  float* maskb = (float*)(ws + ((size_t)1 << 20));
  float* vp1   = (float*)(ws + ((size_t)2 << 20));
  u16* Qb   = (u16*)(ws + ((size_t)3 << 20));          // 512 KB
  u16* Kb   = (u16*)(ws + ((size_t)3 << 20) + 524288);
  u16* VPb  = (u16*)(ws + ((size_t)4 << 20));
  u16* VPT  = (u16*)(ws + ((size_t)4 << 20) + 524288);
  u16* EFNb = (u16*)(ws + ((size_t)5 << 20));
  u16* w1p  = (u16*)(ws + ((size_t)6 << 20));
  u16* w2p  = w1p + 65536;
  u16* wqA  = w2p + 65536;      // [g][4][8][512]
  u16* wkA  = wqA + 32768;
  u16* w1A  = wkA + 32768;      // [g][8][16][512]
  u16* w2A  = w1A + 131072;     // [g][4][16][512]

  k_pack<<<dim3(1536), 256, 0, stream>>>(ps_w1, ps_w2, d2p_w1, d2p_w2, wq, wk,
                                         w1p, w2p, wqA, wkA, w1A, w2A);

  for (int g = 0; g < 2; ++g) {
    const float* vpc = g ? (const float*)vp1 : vp_in;
    float* vpn = g ? vp_out : vp1;
    float* eps_g  = eps_base + (size_t)g * 262144;
    float* sims_g = sims_base + (size_t)g * 262144;
    const float* epprev = g ? eps_base : ep_in;

    k_point_sim<<<dim3(1152), 256, 0, stream>>>(vpc,
        w1p + (size_t)g * 32768, w2p + (size_t)g * 32768,
        ps_g1 + g * 256, ps_b1 + g * 256,
        ps_g2 + g * 128, ps_b2 + g * 128,
        ps_w3 + g * 128, ps_b3 + g, s_buf, sims_g);
    if (g) k_rank<<<dim3(2048), 128, 0, stream>>>(s_buf, epprev, maskb);
    k_edge<<<dim3(2048), 128, 0, stream>>>(s_buf, epprev, maskb, g, eps_g);
    k_prep<<<dim3(16), 512, 0, stream>>>(vpc,
        wqA + (size_t)g * 16384, wkA + (size_t)g * 16384, Qb, Kb, VPb, VPT);
    k_attn<<<dim3(64), 256, 0, stream>>>(Qb, Kb, eps_g, EFNb);
    k_d2p<<<dim3(64), 256, 0, stream>>>(EFNb, VPb, VPT,
        w1A + (size_t)g * 65536, d2p_g1 + g * 256, d2p_b1 + g * 256,
        w2A + (size_t)g * 32768, d2p_g2 + g * 128, d2p_b2 + g * 128, vpn);
  }
}

// Round 5
// 135.736 us; speedup vs baseline: 2.5095x; 1.1101x over previous
//
#include <hip/hip_runtime.h>
#include <hip/hip_bf16.h>

typedef unsigned int u32;
typedef unsigned short u16;
typedef float f32x4 __attribute__((ext_vector_type(4)));
typedef float f32x16 __attribute__((ext_vector_type(16)));
typedef short bh8 __attribute__((ext_vector_type(8)));   // 8 bf16 operand frag

#define NB 16
#define NN 128
#define DD 128

__device__ __forceinline__ u16 f2bf(float f) {
  union { float f; u32 u; } x; x.f = f;
  u32 r = (x.u + 0x7fffu + ((x.u >> 16) & 1u)) >> 16;
  return (u16)r;
}
__device__ __forceinline__ float bf2f(u16 h) {
  union { u32 u; float f; } x; x.u = ((u32)h) << 16;
  return x.f;
}
__device__ __forceinline__ float lrelu(float x) { return x >= 0.f ? x : 0.01f * x; }
__device__ __forceinline__ f32x16 zero16() {
  f32x16 v;
  #pragma unroll
  for (int r = 0; r < 16; ++r) v[r] = 0.f;
  return v;
}

// ---------------- unified weight pack/convert ----------------
__global__ void k_pack(const float* __restrict__ ps_w1, const float* __restrict__ ps_w2,
                       const float* __restrict__ d2p_w1, const float* __restrict__ d2p_w2,
                       const float* __restrict__ wq, const float* __restrict__ wk,
                       u16* __restrict__ w1p, u16* __restrict__ w2p,
                       u16* __restrict__ wqA, u16* __restrict__ wkA,
                       u16* __restrict__ w1A, u16* __restrict__ w2A)
{
  int idx = blockIdx.x * 256 + threadIdx.x;
  if (idx < 65536) {
    int r = idx & 7, lane = (idx >> 3) & 63, f = (idx >> 9) & 63, g = idx >> 15;
    int ct = f >> 3, ks = f & 7;
    int c = ct * 32 + (lane & 31), d = ks * 16 + (lane >> 5) * 8 + r;
    w1p[idx] = f2bf(ps_w1[(size_t)g * 32768 + c * 128 + d]);
    return;
  }
  idx -= 65536;
  if (idx < 65536) {
    int r = idx & 7, lane = (idx >> 3) & 63, f = (idx >> 9) & 63, g = idx >> 15;
    int et = f >> 4, ks2 = f & 15;
    int e = et * 32 + (lane & 31), c = ks2 * 16 + (lane >> 5) * 8 + r;
    w2p[idx] = f2bf(ps_w2[(size_t)g * 32768 + e * 256 + c]);
    return;
  }
  idx -= 65536;
  if (idx < 32768) {
    int r = idx & 7, lane = (idx >> 3) & 63, ks = (idx >> 9) & 7, ot = (idx >> 12) & 3, g = idx >> 14;
    int o = ot * 32 + (lane & 31), d = ks * 16 + (lane >> 5) * 8 + r;
    wqA[idx] = f2bf(wq[(size_t)g * 16384 + o * 128 + d]);
    return;
  }
  idx -= 32768;
  if (idx < 32768) {
    int r = idx & 7, lane = (idx >> 3) & 63, ks = (idx >> 9) & 7, ot = (idx >> 12) & 3, g = idx >> 14;
    int o = ot * 32 + (lane & 31), d = ks * 16 + (lane >> 5) * 8 + r;
    wkA[idx] = f2bf(wk[(size_t)g * 16384 + o * 128 + d]);
    return;
  }
  idx -= 32768;
  if (idx < 131072) {
    int r = idx & 7, lane = (idx >> 3) & 63, ks = (idx >> 9) & 15, ot = (idx >> 13) & 7, g = idx >> 16;
    int o = ot * 32 + (lane & 31), q = ks * 16 + (lane >> 5) * 8 + r;
    w1A[idx] = f2bf(d2p_w1[(size_t)g * 65536 + o * 256 + q]);
    return;
  }
  idx -= 131072;
  if (idx < 65536) {
    int r = idx & 7, lane = (idx >> 3) & 63, ks = (idx >> 9) & 15, ot = (idx >> 13) & 3, g = idx >> 15;
    int o = ot * 32 + (lane & 31), q = ks * 16 + (lane >> 5) * 8 + r;
    w2A[idx] = f2bf(d2p_w2[(size_t)g * 32768 + o * 256 + q]);
    return;
  }
}

// ---------------- point-sim: software-pipelined, 1 barrier per m-tile ----------------
__global__ __launch_bounds__(256, 2)
void k_point_sim(const float* __restrict__ vp,
                 const u16* __restrict__ w1p, const u16* __restrict__ w2p,
                 const float* __restrict__ g1v, const float* __restrict__ b1v,
                 const float* __restrict__ g2v, const float* __restrict__ b2v,
                 const float* __restrict__ w3v, const float* __restrict__ b3v,
                 float* __restrict__ s_out, float* __restrict__ sims_out)
{
  const int bid = blockIdx.x;
  const int half = bid & 1;
  int rem = (bid >> 1) % 36;
  const int b = (bid >> 1) / 36;
  int ti = 0;
  while (rem >= 8 - ti) { rem -= 8 - ti; ++ti; }
  const int tj = ti + rem;

  const int t = threadIdx.x;
  const int lane = t & 63;
  const int w = t >> 6;
  const int p_l = lane & 31;
  const int hi = lane >> 5;
  const float rsbn = rsqrtf(1.0f + 1e-5f);

  __shared__ u16 Adiff[2][32 * 128];     // 16 KB double-buffered diff
  __shared__ u16 HL[2][32 * 256];        // 32 KB double-buffered h1
  __shared__ float sc1[256], bb1[256];
  __shared__ float sc2[128], bb2[128], w3s[128];
  __shared__ float sred[2][4][32];
  __shared__ float simv[128], svv[128];

  sc1[t] = g1v[t] * rsbn; bb1[t] = b1v[t];
  if (t < 128) { sc2[t] = g2v[t] * rsbn; bb2[t] = b2v[t]; w3s[t] = w3v[t]; }

  bh8 a1[2][8];
  #pragma unroll
  for (int c2 = 0; c2 < 2; ++c2)
    #pragma unroll
    for (int ks = 0; ks < 8; ++ks)
      a1[c2][ks] = *(const bh8*)(w1p + (((w * 2 + c2) * 8 + ks) * 64 + lane) * 8);
  bh8 a2[16];
  #pragma unroll
  for (int ks = 0; ks < 16; ++ks)
    a2[ks] = *(const bh8*)(w2p + ((w * 16 + ks) * 64 + lane) * 8);

  const int mtA = half * 4;
  const float* vpb = vp + (size_t)b * NN * DD;

  auto diffgen = [&](int mt, int buf) {
    int p = t >> 3, dseg = t & 7;
    int il = mt * 2 + (p >> 4), jl = p & 15;
    int i = ti * 16 + il, j = tj * 16 + jl;
    const float4* vi = (const float4*)(vpb + i * DD + dseg * 16);
    const float4* vj = (const float4*)(vpb + j * DD + dseg * 16);
    float rs = 0.f;
    u32 pw[8];
    #pragma unroll
    for (int c = 0; c < 4; ++c) {
      float4 av = vi[c], bv = vj[c];
      float d0 = av.x - bv.x; d0 *= d0;
      float d1 = av.y - bv.y; d1 *= d1;
      float d2 = av.z - bv.z; d2 *= d2;
      float d3 = av.w - bv.w; d3 *= d3;
      rs += d0 + d1 + d2 + d3;
      pw[c * 2]     = (u32)f2bf(d0) | ((u32)f2bf(d1) << 16);
      pw[c * 2 + 1] = (u32)f2bf(d2) | ((u32)f2bf(d3) << 16);
    }
    int base = p * 256;
    int off0 = (dseg * 32) ^ ((p & 15) << 4);
    int off1 = (dseg * 32 + 16) ^ ((p & 15) << 4);
    uint4 q0; q0.x = pw[0]; q0.y = pw[1]; q0.z = pw[2]; q0.w = pw[3];
    uint4 q1; q1.x = pw[4]; q1.y = pw[5]; q1.z = pw[6]; q1.w = pw[7];
    *(uint4*)((char*)Adiff[buf] + base + off0) = q0;
    *(uint4*)((char*)Adiff[buf] + base + off1) = q1;
    rs += __shfl_xor(rs, 1);
    rs += __shfl_xor(rs, 2);
    rs += __shfl_xor(rs, 4);
    if ((t & 7) == 0) simv[(mt - mtA) * 32 + p] = rs;
  };

  auto do_l2 = [&](int src) {    // layer2 from HL[src] for tile (whose parity = src)
    f32x16 acc2 = zero16();
    #pragma unroll
    for (int ks2 = 0; ks2 < 16; ++ks2) {
      int byte = p_l * 512 + ((ks2 * 32 + hi * 16) ^ (p_l << 4));
      bh8 bf = *(const bh8*)((const char*)HL[src] + byte);
      acc2 = __builtin_amdgcn_mfma_f32_32x32x16_bf16(a2[ks2], bf, acc2, 0, 0, 0);
    }
    float psum = 0.f;
    #pragma unroll
    for (int r = 0; r < 16; ++r) {
      int e = w * 32 + (r & 3) + 8 * (r >> 2) + 4 * hi;
      float v = lrelu(acc2[r] * sc2[e] + bb2[e]);
      psum += v * w3s[e];
    }
    psum += __shfl_xor(psum, 32);
    if (hi == 0) sred[src][w][p_l] = psum;
  };

  auto s_final = [&](int ml) {
    if (t < 32) {
      float z = sred[ml & 1][0][t] + sred[ml & 1][1][t] + sred[ml & 1][2][t]
              + sred[ml & 1][3][t] + b3v[0];
      svv[ml * 32 + t] = 1.f / (1.f + __expf(-z));
    }
  };

  diffgen(mtA, 0);
  __syncthreads();

  #pragma unroll
  for (int m = 0; m < 4; ++m) {
    const int cur = m & 1;
    // layer1 for tile m from Adiff[cur]
    f32x16 acc1[2];
    acc1[0] = zero16(); acc1[1] = zero16();
    #pragma unroll
    for (int ks = 0; ks < 8; ++ks) {
      int byte = p_l * 256 + ((ks * 32 + hi * 16) ^ ((p_l & 15) << 4));
      bh8 bf = *(const bh8*)((const char*)Adiff[cur] + byte);
      acc1[0] = __builtin_amdgcn_mfma_f32_32x32x16_bf16(a1[0][ks], bf, acc1[0], 0, 0, 0);
      acc1[1] = __builtin_amdgcn_mfma_f32_32x32x16_bf16(a1[1][ks], bf, acc1[1], 0, 0, 0);
    }
    // diff for tile m+1 into the other buffer (independent: overlaps with L1/L2 MFMA)
    if (m < 3) diffgen(mtA + m + 1, cur ^ 1);
    // layer2 for tile m-1 from HL[cur^1] (written last iter, barrier-separated)
    if (m > 0) do_l2(cur ^ 1);
    if (m >= 2) s_final(m - 2);
    // epilogue1: acc1 -> HL[cur]
    #pragma unroll
    for (int c2 = 0; c2 < 2; ++c2) {
      #pragma unroll
      for (int g4 = 0; g4 < 4; ++g4) {
        int c0 = (w * 2 + c2) * 32 + g4 * 8 + hi * 4;
        float v0 = lrelu(acc1[c2][g4 * 4 + 0] * sc1[c0 + 0] + bb1[c0 + 0]);
        float v1 = lrelu(acc1[c2][g4 * 4 + 1] * sc1[c0 + 1] + bb1[c0 + 1]);
        float v2 = lrelu(acc1[c2][g4 * 4 + 2] * sc1[c0 + 2] + bb1[c0 + 2]);
        float v3 = lrelu(acc1[c2][g4 * 4 + 3] * sc1[c0 + 3] + bb1[c0 + 3]);
        uint2 pk;
        pk.x = (u32)f2bf(v0) | ((u32)f2bf(v1) << 16);
        pk.y = (u32)f2bf(v2) | ((u32)f2bf(v3) << 16);
        int byte = p_l * 512 + ((c0 * 2) ^ (p_l << 4));
        *(uint2*)((char*)HL[cur] + byte) = pk;
      }
    }
    __syncthreads();
  }
  // drain: layer2 for tile 3 (HL[1]), then finals
  do_l2(1);
  s_final(2);
  __syncthreads();
  s_final(3);
  __syncthreads();

  // write-out
  {
    int idx = t & 127;
    int mm = idx >> 5, pp = idx & 31;
    int mt = mtA + mm;
    int i = ti * 16 + mt * 2 + (pp >> 4);
    int j = tj * 16 + (pp & 15);
    float sv = svv[idx];
    float sm = -simv[idx];
    if (t < 128) {
      s_out[(size_t)(b * NN + i) * NN + j] = sv;
      sims_out[(size_t)(b * NN + i) * NN + j] = sm;
    } else if (ti != tj) {
      s_out[(size_t)(b * NN + j) * NN + i] = sv;
      sims_out[(size_t)(b * NN + j) * NN + i] = sm;
    }
  }
}

// ---------------- top-k rank scatter ----------------
__global__ void k_rank(const float* __restrict__ s_buf, const float* __restrict__ ep_prev,
                       float* __restrict__ mask)
{
  const int b = blockIdx.x >> 7, n = blockIdx.x & 127, t = threadIdx.x;
  __shared__ float ev[NN];
  size_t row = (size_t)(b * NN + n) * NN;
  float v = s_buf[row + t] * ((t == n) ? 0.f : ep_prev[row + t]);
  ev[t] = v;
  __syncthreads();
  int r = 0;
  for (int j = 0; j < NN; ++j) {
    float vj = ev[j];
    r += (vj > v) || (vj == v && j < t);
  }
  if (r < 115) mask[(size_t)(b * NN + t) * NN + r] = 1.0f;
}

// ---------------- fused: edge normalization (blocks 0..1023, 2 rows each)
//                  + prep (blocks 1024..1087: vp->bf16 + q/k proj) ----------------
__global__ __launch_bounds__(256)
void k_edge_prep(const float* __restrict__ s_buf, const float* __restrict__ ep_prev,
                 float* __restrict__ maskb, int use_mask, float* __restrict__ eps_out,
                 const float* __restrict__ vp,
                 const u16* __restrict__ wqA, const u16* __restrict__ wkA,
                 u16* __restrict__ Qb, u16* __restrict__ Kb,
                 u16* __restrict__ VPb, u16* __restrict__ VPT)
{
  __shared__ char shm[8448];
  const int t = threadIdx.x;

  if (blockIdx.x < 1024) {
    // ---- edge: 2 rows per block ----
    float* red  = (float*)shm;        // [2][2][2]
    float* red2 = (float*)shm + 8;    // [2][2]
    const int rr = t >> 7, tl = t & 127;
    const int rowid = blockIdx.x * 2 + rr;
    const int i = rowid & 127;
    const int wl = (t >> 6) & 1;
    size_t row = (size_t)rowid * 128;
    float ep0 = (tl == i) ? 0.f : ep_prev[row + tl];
    float e = s_buf[row + tl] * ep0;
    if (use_mask) e *= maskb[row + tl];
    else maskb[row + tl] = 0.f;
    float a = ep0, c = fabsf(e);
    #pragma unroll
    for (int o = 32; o; o >>= 1) { a += __shfl_xor(a, o); c += __shfl_xor(c, o); }
    if ((t & 63) == 0) { red[(rr * 2 + wl) * 2 + 0] = a; red[(rr * 2 + wl) * 2 + 1] = c; }
    __syncthreads();
    float epsum = red[(rr * 2) * 2] + red[(rr * 2 + 1) * 2];
    float l1 = red[(rr * 2) * 2 + 1] + red[(rr * 2 + 1) * 2 + 1];
    e = e / fmaxf(l1, 1e-12f) * epsum;
    e += ((tl == i) ? 1.f : 0.f) + 1e-6f;
    float d = e;
    #pragma unroll
    for (int o = 32; o; o >>= 1) d += __shfl_xor(d, o);
    if ((t & 63) == 0) red2[rr * 2 + wl] = d;
    __syncthreads();
    eps_out[row + tl] = e / (red2[rr * 2] + red2[rr * 2 + 1]);
    return;
  }

  // ---- prep: block (b, nt) converts rows nt*32..+32 and computes q/k for them ----
  u16* VPs = (u16*)shm;   // [32][128] bf16 swizzled (8 KB)
  const int pb = blockIdx.x - 1024;
  const int b = pb >> 2, nt = pb & 3;
  const int w = t >> 6, lane = t & 63, l31 = lane & 31, hi = lane >> 5;
  const float* vpb = vp + (size_t)b * 16384 + (size_t)nt * 32 * 128;

  {
    int r = t >> 3, cseg = t & 7;
    float v[16];
    const float4* src = (const float4*)(vpb + r * 128 + cseg * 16);
    #pragma unroll
    for (int c = 0; c < 4; ++c) {
      float4 a = src[c];
      v[c * 4 + 0] = a.x; v[c * 4 + 1] = a.y; v[c * 4 + 2] = a.z; v[c * 4 + 3] = a.w;
    }
    uint4 pk0, pk1;
    u32* p0 = (u32*)&pk0; u32* p1 = (u32*)&pk1;
    #pragma unroll
    for (int k = 0; k < 4; ++k) {
      p0[k] = (u32)f2bf(v[k * 2 + 0]) | ((u32)f2bf(v[k * 2 + 1]) << 16);
      p1[k] = (u32)f2bf(v[8 + k * 2 + 0]) | ((u32)f2bf(v[8 + k * 2 + 1]) << 16);
    }
    u16* vb = VPb + (size_t)b * 16384 + (nt * 32 + r) * 128 + cseg * 16;
    *(uint4*)(vb) = pk0;
    *(uint4*)(vb + 8) = pk1;
    *(uint4*)((char*)VPs + r * 256 + ((cseg * 32) ^ ((r & 15) << 4))) = pk0;
    *(uint4*)((char*)VPs + r * 256 + ((cseg * 32 + 16) ^ ((r & 15) << 4))) = pk1;
  }
  __syncthreads();

  // transposed VPT[col][nt*32..+32]
  {
    int col = t >> 1, hh = t & 1;
    u16 tmp[16];
    #pragma unroll
    for (int rr2 = 0; rr2 < 16; ++rr2) {
      int row = hh * 16 + rr2;
      tmp[rr2] = *(const u16*)((char*)VPs + row * 256 + ((col * 2) ^ ((row & 15) << 4)));
    }
    *(uint4*)(VPT + (size_t)b * 16384 + col * 128 + nt * 32 + hh * 16) = *(uint4*)&tmp[0];
    *(uint4*)(VPT + (size_t)b * 16384 + col * 128 + nt * 32 + hh * 16 + 8) = *(uint4*)&tmp[8];
  }

  // q/k GEMM for this quarter's 32 rows: wave -> (isK = w>>1, 2 o-tiles)
  {
    const int isK = w >> 1;
    const int otp = (w & 1) * 2;
    const u16* wA = isK ? wkA : wqA;
    u16* DST = (isK ? Kb : Qb) + (size_t)b * 16384;
    bh8 bf[8];
    #pragma unroll
    for (int ks = 0; ks < 8; ++ks)
      bf[ks] = *(const bh8*)((char*)VPs + l31 * 256 + (((ks * 32) + hi * 16) ^ ((l31 & 15) << 4)));
    #pragma unroll
    for (int oo = 0; oo < 2; ++oo) {
      int ot = otp + oo;
      f32x16 acc = zero16();
      #pragma unroll
      for (int ks = 0; ks < 8; ++ks) {
        bh8 af = *(const bh8*)(wA + ((size_t)(ot * 8 + ks) * 64 + lane) * 8);
        acc = __builtin_amdgcn_mfma_f32_32x32x16_bf16(af, bf[ks], acc, 0, 0, 0);
      }
      int n = nt * 32 + l31;
      #pragma unroll
      for (int q4 = 0; q4 < 4; ++q4) {
        int o0 = ot * 32 + q4 * 8 + hi * 4;
        uint2 pk;
        pk.x = (u32)f2bf(acc[q4 * 4 + 0]) | ((u32)f2bf(acc[q4 * 4 + 1]) << 16);
        pk.y = (u32)f2bf(acc[q4 * 4 + 2]) | ((u32)f2bf(acc[q4 * 4 + 3]) << 16);
        *(uint2*)(DST + n * 128 + o0) = pk;
      }
    }
  }
}

// ---------------- fused attn + fuse + l1 + aggr + MLP1 + MLP2 ----------------
// grid = 16 b * 4 i-chunks = 64 blocks, 256 threads (4 waves); EFN stays in LDS
__global__ __launch_bounds__(256)
void k_attn_d2p(const u16* __restrict__ Qb, const u16* __restrict__ Kb,
                const float* __restrict__ eps_g,
                const u16* __restrict__ VPb, const u16* __restrict__ VPT,
                const u16* __restrict__ w1A, const float* __restrict__ g1v, const float* __restrict__ b1v,
                const u16* __restrict__ w2A, const float* __restrict__ g2v, const float* __restrict__ b2v,
                float* __restrict__ vpn)
{
  __shared__ char shm[40960];
  u16* att  = (u16*)shm;             // 32 KB [4 waves][32][128] swz  (dead after phase B)
  u16* AG   = (u16*)shm;             // 8 KB  aggr, reuses att[0..8K)
  u16* HB   = (u16*)(shm + 8192);    // 16 KB h1,  reuses att[8K..24K)
  u16* EFNl = (u16*)(shm + 32768);   // 8 KB fused+normalized edge (bf16, swz)

  const int b = blockIdx.x >> 2;
  const int ch = blockIdx.x & 3;
  const int t = threadIdx.x;
  const int w = t >> 6;
  const int lane = t & 63;
  const int l31 = lane & 31;
  const int hi = lane >> 5;
  const float rsbn = rsqrtf(1.f + 1e-5f);

  // ---- A: per-head logits + in-lane softmax + 2-head partial sum ----
  {
    float asum[64];
    #pragma unroll
    for (int z = 0; z < 64; ++z) asum[z] = 0.f;
    const u16* Qrow = Qb + (size_t)b * 16384 + (ch * 32 + l31) * 128;
    #pragma unroll
    for (int hh = 0; hh < 2; ++hh) {
      int h = w * 2 + hh;
      bh8 qf = *(const bh8*)(Qrow + h * 16 + hi * 8);
      f32x16 lg[4];
      #pragma unroll
      for (int jt = 0; jt < 4; ++jt) {
        bh8 kf = *(const bh8*)(Kb + (size_t)b * 16384 + (jt * 32 + l31) * 128 + h * 16 + hi * 8);
        f32x16 zz = zero16();
        lg[jt] = __builtin_amdgcn_mfma_f32_32x32x16_bf16(kf, qf, zz, 0, 0, 0);
      }
      float m = lg[0][0];
      #pragma unroll
      for (int jt = 0; jt < 4; ++jt)
        #pragma unroll
        for (int r = 0; r < 16; ++r) m = fmaxf(m, lg[jt][r]);
      m = fmaxf(m, __shfl_xor(m, 32));
      float sum = 0.f;
      #pragma unroll
      for (int jt = 0; jt < 4; ++jt)
        #pragma unroll
        for (int r = 0; r < 16; ++r) {
          float e = __expf((lg[jt][r] - m) * 0.25f);
          lg[jt][r] = e;
          sum += e;
        }
      sum += __shfl_xor(sum, 32);
      float inv = 1.f / sum;
      #pragma unroll
      for (int jt = 0; jt < 4; ++jt)
        #pragma unroll
        for (int r = 0; r < 16; ++r) asum[jt * 16 + r] += lg[jt][r] * inv;
    }
    #pragma unroll
    for (int jt = 0; jt < 4; ++jt)
      #pragma unroll
      for (int q4 = 0; q4 < 4; ++q4) {
        int j0 = jt * 32 + q4 * 8 + hi * 4;
        uint2 pk;
        pk.x = (u32)f2bf(asum[jt * 16 + q4 * 4 + 0]) | ((u32)f2bf(asum[jt * 16 + q4 * 4 + 1]) << 16);
        pk.y = (u32)f2bf(asum[jt * 16 + q4 * 4 + 2]) | ((u32)f2bf(asum[jt * 16 + q4 * 4 + 3]) << 16);
        *(uint2*)((char*)att + (w * 32 + l31) * 256 + ((j0 * 2) ^ ((l31 & 15) << 4))) = pk;
      }
  }
  __syncthreads();

  // ---- B: combine 4 wave-partials, fuse with eps, l1-normalize -> EFNl ----
  {
    int il = t >> 3, jseg = t & 7;
    int i = ch * 32 + il;
    float a[16];
    #pragma unroll
    for (int z = 0; z < 16; ++z) a[z] = 0.f;
    #pragma unroll
    for (int ww = 0; ww < 4; ++ww) {
      #pragma unroll
      for (int c = 0; c < 2; ++c) {
        uint4 v = *(const uint4*)((char*)att + (ww * 32 + il) * 256 + (((jseg * 32) + c * 16) ^ ((il & 15) << 4)));
        u32 uu[4] = {v.x, v.y, v.z, v.w};
        #pragma unroll
        for (int k = 0; k < 4; ++k) {
          a[c * 8 + k * 2 + 0] += bf2f((u16)(uu[k] & 0xffff));
          a[c * 8 + k * 2 + 1] += bf2f((u16)(uu[k] >> 16));
        }
      }
    }
    const float* erow = eps_g + ((size_t)b * 128 + i) * 128 + jseg * 16;
    float f[16];
    float s = 0.f;
    #pragma unroll
    for (int c = 0; c < 4; ++c) {
      float4 ev = *(const float4*)(erow + c * 4);
      float evs[4] = {ev.x, ev.y, ev.z, ev.w};
      #pragma unroll
      for (int k = 0; k < 4; ++k) {
        int jj = jseg * 16 + c * 4 + k;
        float fv = 0.5f * (evs[k] + a[c * 4 + k] * 0.125f);
        if (jj == i) fv = 0.f;
        f[c * 4 + k] = fv;
        s += fabsf(fv);
      }
    }
    s += __shfl_xor(s, 1);
    s += __shfl_xor(s, 2);
    s += __shfl_xor(s, 4);
    float inv = 1.f / fmaxf(s, 1e-12f);
    uint4 o0, o1;
    u32* op = (u32*)&o0;
    u32* op1 = (u32*)&o1;
    #pragma unroll
    for (int k = 0; k < 4; ++k) {
      op[k]  = (u32)f2bf(f[k * 2 + 0] * inv) | ((u32)f2bf(f[k * 2 + 1] * inv) << 16);
      op1[k] = (u32)f2bf(f[8 + k * 2 + 0] * inv) | ((u32)f2bf(f[8 + k * 2 + 1] * inv) << 16);
    }
    __syncthreads();   // att reads done before EFNl/AG phases overwrite nothing; keep order safe
    *(uint4*)((char*)EFNl + il * 256 + ((jseg * 32) ^ ((il & 15) << 4))) = o0;
    *(uint4*)((char*)EFNl + il * 256 + ((jseg * 32 + 16) ^ ((il & 15) << 4))) = o1;
  }
  __syncthreads();

  // ---- C: aggr C[d][i] = sum_j vpT[d][j] * efn[i][j]  (wave w = d-tile) ----
  {
    const u16* vtrow = VPT + (size_t)b * 16384 + (w * 32 + l31) * 128;
    f32x16 acc = zero16();
    #pragma unroll
    for (int ks = 0; ks < 8; ++ks) {
      bh8 af = *(const bh8*)(vtrow + ks * 16 + hi * 8);
      bh8 bf = *(const bh8*)((char*)EFNl + l31 * 256 + (((ks * 32) + hi * 16) ^ ((l31 & 15) << 4)));
      acc = __builtin_amdgcn_mfma_f32_32x32x16_bf16(af, bf, acc, 0, 0, 0);
    }
    #pragma unroll
    for (int q4 = 0; q4 < 4; ++q4) {
      int d0 = w * 32 + q4 * 8 + hi * 4;
      uint2 pk;
      pk.x = (u32)f2bf(acc[q4 * 4 + 0]) | ((u32)f2bf(acc[q4 * 4 + 1]) << 16);
      pk.y = (u32)f2bf(acc[q4 * 4 + 2]) | ((u32)f2bf(acc[q4 * 4 + 3]) << 16);
      *(uint2*)((char*)AG + l31 * 256 + ((d0 * 2) ^ ((l31 & 15) << 4))) = pk;
    }
  }
  __syncthreads();

  // ---- D: MLP1 C[o][i] = sum_q w1[o][q] feat[i][q], feat = [vp | aggr] ----
  {
    const u16* vprow = VPb + (size_t)b * 16384 + (ch * 32 + l31) * 128;
    f32x16 acc0 = zero16(), acc1v = zero16();
    #pragma unroll
    for (int ks = 0; ks < 16; ++ks) {
      bh8 a0 = *(const bh8*)(w1A + ((size_t)((w * 2 + 0) * 16 + ks)) * 512 + lane * 8);
      bh8 a1 = *(const bh8*)(w1A + ((size_t)((w * 2 + 1) * 16 + ks)) * 512 + lane * 8);
      bh8 bf;
      if (ks < 8) bf = *(const bh8*)(vprow + ks * 16 + hi * 8);
      else bf = *(const bh8*)((char*)AG + l31 * 256 + ((((ks - 8) * 32) + hi * 16) ^ ((l31 & 15) << 4)));
      acc0 = __builtin_amdgcn_mfma_f32_32x32x16_bf16(a0, bf, acc0, 0, 0, 0);
      acc1v = __builtin_amdgcn_mfma_f32_32x32x16_bf16(a1, bf, acc1v, 0, 0, 0);
    }
    #pragma unroll
    for (int oo = 0; oo < 2; ++oo) {
      const f32x16& acc = oo ? acc1v : acc0;
      #pragma unroll
      for (int q4 = 0; q4 < 4; ++q4) {
        int o0 = (w * 2 + oo) * 32 + q4 * 8 + hi * 4;
        float4 gg = *(const float4*)(g1v + o0);
        float4 bb = *(const float4*)(b1v + o0);
        float v0 = lrelu(acc[q4 * 4 + 0] * (gg.x * rsbn) + bb.x);
        float v1 = lrelu(acc[q4 * 4 + 1] * (gg.y * rsbn) + bb.y);
        float v2 = lrelu(acc[q4 * 4 + 2] * (gg.z * rsbn) + bb.z);
        float v3 = lrelu(acc[q4 * 4 + 3] * (gg.w * rsbn) + bb.w);
        uint2 pk;
        pk.x = (u32)f2bf(v0) | ((u32)f2bf(v1) << 16);
        pk.y = (u32)f2bf(v2) | ((u32)f2bf(v3) << 16);
        *(uint2*)((char*)HB + l31 * 512 + ((o0 * 2) ^ (l31 << 4))) = pk;
      }
    }
  }
  __syncthreads();

  // ---- E: MLP2 C[o2][i] -> vpn ----
  {
    f32x16 acc = zero16();
    #pragma unroll
    for (int ks = 0; ks < 16; ++ks) {
      bh8 af = *(const bh8*)(w2A + ((size_t)(w * 16 + ks)) * 512 + lane * 8);
      bh8 bf = *(const bh8*)((char*)HB + l31 * 512 + (((ks * 32) + hi * 16) ^ (l31 << 4)));
      acc = __builtin_amdgcn_mfma_f32_32x32x16_bf16(af, bf, acc, 0, 0, 0);
    }
    int i = ch * 32 + l31;
    #pragma unroll
    for (int q4 = 0; q4 < 4; ++q4) {
      int o0 = w * 32 + q4 * 8 + hi * 4;
      float4 gg = *(const float4*)(g2v + o0);
      float4 bb = *(const float4*)(b2v + o0);
      float4 ov;
      ov.x = lrelu(acc[q4 * 4 + 0] * (gg.x * rsbn) + bb.x);
      ov.y = lrelu(acc[q4 * 4 + 1] * (gg.y * rsbn) + bb.y);
      ov.z = lrelu(acc[q4 * 4 + 2] * (gg.z * rsbn) + bb.z);
      ov.w = lrelu(acc[q4 * 4 + 3] * (gg.w * rsbn) + bb.w);
      *(float4*)(vpn + ((size_t)b * 128 + i) * 128 + o0) = ov;
    }
  }
}

extern "C" void kernel_launch(void* const* d_in, const int* in_sizes, int n_in,
                              void* d_out, int out_size, void* d_ws, size_t ws_size,
                              hipStream_t stream)
{
  (void)in_sizes; (void)n_in; (void)out_size; (void)ws_size;
  const float* vp_in  = (const float*)d_in[0];
  const float* ep_in  = (const float*)d_in[1];
  const float* ps_w1  = (const float*)d_in[2];
  const float* ps_g1  = (const float*)d_in[3];
  const float* ps_b1  = (const float*)d_in[4];
  const float* ps_w2  = (const float*)d_in[5];
  const float* ps_g2  = (const float*)d_in[6];
  const float* ps_b2  = (const float*)d_in[7];
  const float* ps_w3  = (const float*)d_in[8];
  const float* ps_b3  = (const float*)d_in[9];
  const float* d2p_w1 = (const float*)d_in[10];
  const float* d2p_g1 = (const float*)d_in[11];
  const float* d2p_b1 = (const float*)d_in[12];
  const float* d2p_w2 = (const float*)d_in[13];
  const float* d2p_g2 = (const float*)d_in[14];
  const float* d2p_b2 = (const float*)d_in[15];
  const float* wq     = (const float*)d_in[16];
  const float* wk     = (const float*)d_in[17];

  float* out = (float*)d_out;
  float* eps_base  = out;                 // [2][16][128][128]
  float* sims_base = out + 524288;        // [2][16][128][128]
  float* vp_out    = out + 1048576;       // [16][128][128]

  char* ws = (char*)d_ws;
  float* s_buf = (float*)(ws + ((size_t)0 << 20));
  float* maskb = (float*)(ws + ((size_t)1 << 20));
  float* vp1   = (float*)(ws + ((size_t)2 << 20));
  u16* Qb   = (u16*)(ws + ((size_t)3 << 20));          // 512 KB
  u16* Kb   = (u16*)(ws + ((size_t)3 << 20) + 524288);
  u16* VPb  = (u16*)(ws + ((size_t)4 << 20));
  u16* VPT  = (u16*)(ws + ((size_t)4 << 20) + 524288);
  u16* w1p  = (u16*)(ws + ((size_t)5 << 20));
  u16* w2p  = w1p + 65536;
  u16* wqA  = w2p + 65536;      // [g][4][8][512]
  u16* wkA  = wqA + 32768;
  u16* w1A  = wkA + 32768;      // [g][8][16][512]
  u16* w2A  = w1A + 131072;     // [g][4][16][512]

  k_pack<<<dim3(1536), 256, 0, stream>>>(ps_w1, ps_w2, d2p_w1, d2p_w2, wq, wk,
                                         w1p, w2p, wqA, wkA, w1A, w2A);

  for (int g = 0; g < 2; ++g) {
    const float* vpc = g ? (const float*)vp1 : vp_in;
    float* vpn = g ? vp_out : vp1;
    float* eps_g  = eps_base + (size_t)g * 262144;
    float* sims_g = sims_base + (size_t)g * 262144;
    const float* epprev = g ? eps_base : ep_in;

    k_point_sim<<<dim3(1152), 256, 0, stream>>>(vpc,
        w1p + (size_t)g * 32768, w2p + (size_t)g * 32768,
        ps_g1 + g * 256, ps_b1 + g * 256,
        ps_g2 + g * 128, ps_b2 + g * 128,
        ps_w3 + g * 128, ps_b3 + g, s_buf, sims_g);
    if (g) k_rank<<<dim3(2048), 128, 0, stream>>>(s_buf, epprev, maskb);
    k_edge_prep<<<dim3(1088), 256, 0, stream>>>(s_buf, epprev, maskb, g, eps_g,
        vpc, wqA + (size_t)g * 16384, wkA + (size_t)g * 16384, Qb, Kb, VPb, VPT);
    k_attn_d2p<<<dim3(64), 256, 0, stream>>>(Qb, Kb, eps_g, VPb, VPT,
        w1A + (size_t)g * 65536, d2p_g1 + g * 256, d2p_b1 + g * 256,
        w2A + (size_t)g * 32768, d2p_g2 + g * 128, d2p_b2 + g * 128, vpn);
  }
}